// Round 1
// baseline (392.039 us; speedup 1.0000x reference)
//
#include <hip/hip_runtime.h>
#include <hip/hip_bf16.h>
#include <stdint.h>

#define VOCAB 50257
#define WD 300
#define HID 256
#define NTREE 256
#define LEAVES 1024
#define KP1 320              // word dim padded to mult of 32
#define MP 50304             // vocab rows padded to mult of 128 (393*128)
#define NLEAF (NTREE * LEAVES)   // 262144

using bf16 = __hip_bfloat16;
typedef __attribute__((ext_vector_type(4))) float f32x4;
typedef __attribute__((ext_vector_type(8))) short bf16x8;

// ---------- async global->LDS 16B helper (wave-uniform LDS base + lane*16) ----
__device__ __forceinline__ void async_load16(const void* gptr, void* ldsptr) {
    __builtin_amdgcn_global_load_lds(
        (const __attribute__((address_space(1))) uint32_t*)(uintptr_t)gptr,
        (__attribute__((address_space(3))) uint32_t*)ldsptr,
        16, 0, 0);
}

// ---------- prep: emb fp32 [VOCAB x 300] -> bf16 [MP x 320], zero padded ------
__global__ void prep_emb(const float* __restrict__ emb, bf16* __restrict__ out) {
    int idx = blockIdx.x * 256 + threadIdx.x;     // MP*KP1 total, exact grid
    int row = idx / KP1;
    int col = idx - row * KP1;
    float v = (row < VOCAB && col < WD) ? emb[row * WD + col] : 0.0f;
    out[idx] = __float2bfloat16(v);
}

// ---------- prep: W1 [300x256] -> W1^T bf16 [256x320]; W2 [512x256] -> W2^T bf16 [256x512]
__global__ void prep_w(const float* __restrict__ W1, const float* __restrict__ W2,
                       bf16* __restrict__ w1t, bf16* __restrict__ w2t) {
    int idx = blockIdx.x * 256 + threadIdx.x;     // 256*320 + 256*512 = 212992, exact
    if (idx < 256 * KP1) {
        int n = idx / KP1;
        int k = idx - n * KP1;
        float v = (k < WD) ? W1[k * HID + n] : 0.0f;
        w1t[idx] = __float2bfloat16(v);
    } else {
        int j = idx - 256 * KP1;                  // [0, 131072)
        int n = j >> 9;
        int k = j & 511;
        w2t[j] = __float2bfloat16(W2[k * HID + n]);
    }
}

// ---------- gather: h0[r,:] = proj[ids[r],:]  (512B rows, 16B per lane) -------
__global__ void gather_leaves(const int* __restrict__ ids, const bf16* __restrict__ proj,
                              bf16* __restrict__ h0) {
    int t = blockIdx.x * 256 + threadIdx.x;       // NLEAF*32 total, exact
    int r = t >> 5;
    int p = t & 31;
    int id = ids[r];
    const uint4* src = (const uint4*)(proj + (size_t)id * 256) + p;
    uint4* dst = (uint4*)(h0 + (size_t)r * 256) + p;
    *dst = *src;
}

// ---------- GEMM: C[M x 256] = A[M x K] @ BT[256 x K]^T + bias ---------------
// A, BT bf16 row-major (K contiguous, K % 32 == 0, M % 128 == 0).
// 128x128 block tile, 4 waves (2x2), each wave 64x64 via 4x4 mfma 16x16x32 bf16.
template <bool OUT_F32>
__global__ __launch_bounds__(256)
void gemm_bt(const bf16* __restrict__ A, const bf16* __restrict__ BT,
             const float* __restrict__ bias, void* __restrict__ Cout,
             int M, int K) {
    __shared__ bf16 As[128 * 32];   // [m][k] packed, 64B rows
    __shared__ bf16 Bs[128 * 32];   // [n][k] packed

    const int t    = threadIdx.x;
    const int w    = t >> 6;
    const int lane = t & 63;
    const int m0   = blockIdx.x * 128;
    const int n0   = blockIdx.y * 128;
    const int wr   = w >> 1;         // wave row (0..1) -> 64 rows
    const int wc   = w & 1;          // wave col (0..1) -> 64 cols
    const int mi   = lane & 15;
    const int ks   = (lane >> 4) * 8;

    f32x4 acc[4][4] = {};

    for (int k0 = 0; k0 < K; k0 += 32) {
        // stage A tile: 128 rows x 32 k = 8KB = 512 chunks of 16B; 2 issues/thread
        {
            int c0 = t;                       // chunk 0..255
            int row = c0 >> 2, kp = (c0 & 3) * 8;
            async_load16(A + (size_t)(m0 + row) * K + k0 + kp, (char*)As + w * 1024);
            int c1 = t + 256;
            row = c1 >> 2; kp = (c1 & 3) * 8;
            async_load16(A + (size_t)(m0 + row) * K + k0 + kp, (char*)As + 4096 + w * 1024);
            c0 = t;
            row = c0 >> 2; kp = (c0 & 3) * 8;
            async_load16(BT + (size_t)(n0 + row) * K + k0 + kp, (char*)Bs + w * 1024);
            c1 = t + 256;
            row = c1 >> 2; kp = (c1 & 3) * 8;
            async_load16(BT + (size_t)(n0 + row) * K + k0 + kp, (char*)Bs + 4096 + w * 1024);
        }
        __syncthreads();

        bf16x8 af[4], bfr[4];
        #pragma unroll
        for (int r = 0; r < 4; ++r)
            af[r] = *(const bf16x8*)&As[(wr * 64 + r * 16 + mi) * 32 + ks];
        #pragma unroll
        for (int c = 0; c < 4; ++c)
            bfr[c] = *(const bf16x8*)&Bs[(wc * 64 + c * 16 + mi) * 32 + ks];
        #pragma unroll
        for (int r = 0; r < 4; ++r)
            #pragma unroll
            for (int c = 0; c < 4; ++c)
                acc[r][c] = __builtin_amdgcn_mfma_f32_16x16x32_bf16(af[r], bfr[c], acc[r][c], 0, 0, 0);
        __syncthreads();
    }

    // epilogue: C/D layout col = lane&15, row = (lane>>4)*4 + i
    #pragma unroll
    for (int r = 0; r < 4; ++r) {
        int rowb = m0 + wr * 64 + r * 16 + (lane >> 4) * 4;
        #pragma unroll
        for (int c = 0; c < 4; ++c) {
            int col = n0 + wc * 64 + c * 16 + mi;
            float bv = bias[col];
            #pragma unroll
            for (int i = 0; i < 4; ++i) {
                float v = acc[r][c][i] + bv;
                if (OUT_F32)
                    ((float*)Cout)[(size_t)(rowb + i) * 256 + col] = v;
                else
                    ((bf16*)Cout)[(size_t)(rowb + i) * 256 + col] = __float2bfloat16(v);
            }
        }
    }
}

extern "C" void kernel_launch(void* const* d_in, const int* in_sizes, int n_in,
                              void* d_out, int out_size, void* d_ws, size_t ws_size,
                              hipStream_t stream) {
    const int*   ids = (const int*)d_in[0];
    const float* emb = (const float*)d_in[1];
    const float* W1  = (const float*)d_in[2];
    const float* b1  = (const float*)d_in[3];
    const float* W2  = (const float*)d_in[4];
    const float* b2  = (const float*)d_in[5];

    char* ws = (char*)d_ws;
    size_t off = 0;
    bf16* embB = (bf16*)(ws + off); off += (size_t)MP * KP1 * 2;      // 32.2 MB
    bf16* w1t  = (bf16*)(ws + off); off += (size_t)256 * KP1 * 2;     // 160 KB
    bf16* w2t  = (bf16*)(ws + off); off += (size_t)256 * 512 * 2;     // 256 KB
    bf16* proj = (bf16*)(ws + off); off += (size_t)MP * 256 * 2;      // 25.8 MB
    bf16* h0   = (bf16*)(ws + off); off += (size_t)NLEAF * 256 * 2;   // 134 MB
    bf16* h1   = (bf16*)(ws + off); off += (size_t)(NLEAF / 2) * 256 * 2; // 67 MB
    (void)off; (void)ws_size; (void)in_sizes; (void)n_in; (void)out_size;

    // 1) casts / padding / transposes
    prep_emb<<<(MP * KP1) / 256, 256, 0, stream>>>(emb, embB);
    prep_w<<<(256 * KP1 + 256 * 512) / 256, 256, 0, stream>>>(W1, W2, w1t, w2t);

    // 2) projected embedding table: proj = embB @ W1 + b1   [MP x 256] bf16
    gemm_bt<false><<<dim3(MP / 128, 2), 256, 0, stream>>>(embB, w1t, b1, proj, MP, KP1);

    // 3) leaves: h0[r] = proj[ids[r]]
    gather_leaves<<<(NLEAF * 32) / 256, 256, 0, stream>>>(ids, proj, h0);

    // 4) tree levels: view [rows x 256] as [rows/2 x 512], GEMM with W2^T
    bf16* cur = h0;
    bf16* nxt = h1;
    int rows = NLEAF;
    for (int lvl = 0; lvl < 10; ++lvl) {
        int Mo = rows >> 1;
        if (lvl < 9) {
            gemm_bt<false><<<dim3(Mo / 128, 2), 256, 0, stream>>>(cur, w2t, b2, nxt, Mo, 512);
        } else {
            gemm_bt<true><<<dim3(Mo / 128, 2), 256, 0, stream>>>(cur, w2t, b2, d_out, Mo, 512);
        }
        bf16* tmp = cur; cur = nxt; nxt = tmp;
        rows = Mo;
    }
}

// Round 2
// 324.504 us; speedup vs baseline: 1.2081x; 1.2081x over previous
//
#include <hip/hip_runtime.h>
#include <hip/hip_bf16.h>
#include <stdint.h>

#define VOCAB 50257
#define WD 300
#define KP1 320              // word dim padded to mult of 32
#define MP 50432             // vocab rows padded: 394*128 = 197*256
#define NLEAF 262144         // 256 trees * 1024 leaves

using bf16 = __hip_bfloat16;
typedef __attribute__((ext_vector_type(4))) float f32x4;
typedef __attribute__((ext_vector_type(8))) short bf16x8;

// async global->LDS, 16B per lane; LDS dest = wave-uniform base + lane*16
__device__ __forceinline__ void async_load16(const void* g, void* l) {
    __builtin_amdgcn_global_load_lds(
        (const __attribute__((address_space(1))) uint32_t*)(uintptr_t)g,
        (__attribute__((address_space(3))) uint32_t*)l, 16, 0, 0);
}

// ---------- prep: W1 [300x256] -> W1^T bf16 [256x320] (zero-padded k>=300);
//                  W2 [512x256] -> W2^T bf16 [256x512]; plus 64B zero scratch.
__global__ void prep_w(const float* __restrict__ W1, const float* __restrict__ W2,
                       bf16* __restrict__ w1t, bf16* __restrict__ w2t,
                       float* __restrict__ zbuf) {
    int idx = blockIdx.x * 256 + threadIdx.x;     // 256*320 + 256*512 = 212992 exact
    if (idx < 16) zbuf[idx] = 0.0f;
    if (idx < 256 * KP1) {
        int n = idx / KP1;
        int k = idx - n * KP1;
        w1t[idx] = __float2bfloat16(k < WD ? W1[k * 256 + n] : 0.0f);
    } else {
        int j = idx - 256 * KP1;
        int n = j >> 9;
        int k = j & 511;
        w2t[j] = __float2bfloat16(W2[k * 256 + n]);
    }
}

// ---------- GEMM: C[M x 256] = A[M x K] @ BT[256 x K]^T + bias, bf16 out ------
// AMODE 0: A = bf16 [M x K] contiguous
// AMODE 1: A row r = concat(proj[ids[2r]], proj[ids[2r+1]]), K = 512 (leaf fused gather)
// AMODE 2: A = fp32 emb rows (stride 300, valid k<300, rows clamped to VOCAB-1), K = 320
// 128x128 block tile, 4 waves (2x2), wave 64x64 via 4x4 mfma 16x16x32 bf16.
// LDS tiles XOR-swizzled (source-permuted staging) -> <=2-way bank aliasing (free).
template <int AMODE>
__global__ __launch_bounds__(256)
void gemm128(const void* __restrict__ Av, const int* __restrict__ ids,
             const bf16* __restrict__ BT, const float* __restrict__ bias,
             bf16* __restrict__ C, int M, int K, const float* __restrict__ zbuf) {
    constexpr int ABYTES = (AMODE == 2) ? 16384 : 8192;
    __shared__ char smem[ABYTES + 8192];
    char* Asm = smem;
    bf16* Bs  = (bf16*)(smem + ABYTES);

    const int t = threadIdx.x, w = t >> 6, lane = t & 63;
    const int wr = w >> 1, wc = w & 1, mi = lane & 15, q = lane >> 4;
    const int m0 = blockIdx.x * 128, n0 = blockIdx.y * 128;

    int2 idp0 = {0, 0}, idp1 = {0, 0};
    if constexpr (AMODE == 1) {
        idp0 = ((const int2*)ids)[m0 + (t >> 2)];        // leaf pair for row m0 + t/4
        idp1 = ((const int2*)ids)[m0 + 64 + (t >> 2)];   // leaf pair for row m0+64 + t/4
    }

    f32x4 acc[4][4] = {};

    for (int k0 = 0; k0 < K; k0 += 32) {
        // ---- stage A tile ----
        if constexpr (AMODE == 2) {
            const float* A32 = (const float*)Av;
            #pragma unroll
            for (int i = 0; i < 4; ++i) {               // 1024 fp32 chunks (4 floats each)
                int s = i * 256 + t;
                int row = s >> 3;
                int kcd = (s & 7) ^ (row & 7);          // swizzled source chunk
                int k = k0 + kcd * 4;
                int grow = m0 + row; if (grow >= VOCAB) grow = VOCAB - 1;
                const float* g = (k <= 296) ? (A32 + (size_t)grow * WD + k) : zbuf;
                async_load16(g, Asm + i * 4096 + w * 1024);
            }
        } else {
            #pragma unroll
            for (int i = 0; i < 2; ++i) {               // 512 bf16 chunks (8 elems each)
                int s = i * 256 + t;
                int row = s >> 2;
                int kcd = (s & 3) ^ ((row >> 2) & 3);   // swizzled source chunk
                const bf16* g;
                if constexpr (AMODE == 1) {
                    int k = k0 + kcd * 8;               // global k in [k0, k0+32)
                    int sel = k >> 8;                   // which sibling leaf (uniform per iter)
                    int id = (i == 0) ? (sel ? idp0.y : idp0.x)
                                      : (sel ? idp1.y : idp1.x);
                    g = (const bf16*)Av + (size_t)id * 256 + (k & 255);
                } else {
                    g = (const bf16*)Av + (size_t)(m0 + row) * K + k0 + kcd * 8;
                }
                async_load16(g, Asm + i * 4096 + w * 1024);
            }
        }
        // ---- stage B tile (128 cols x 32 k) ----
        #pragma unroll
        for (int i = 0; i < 2; ++i) {
            int s = i * 256 + t;
            int col = s >> 2;
            int kcd = (s & 3) ^ ((col >> 2) & 3);
            async_load16(BT + (size_t)(n0 + col) * K + k0 + kcd * 8,
                         (char*)Bs + i * 4096 + w * 1024);
        }
        __syncthreads();

        // ---- fragments (swizzled slots; <=2-way bank aliasing) ----
        bf16x8 af[4], bfr[4];
        if constexpr (AMODE == 2) {
            const float* As32 = (const float*)Asm;
            #pragma unroll
            for (int r = 0; r < 4; ++r) {
                int row = wr * 64 + r * 16 + mi;
                int sl = row * 8 + ((2 * q) ^ (row & 7));
                f32x4 lo = *(const f32x4*)(As32 + sl * 4);
                f32x4 hi = *(const f32x4*)(As32 + (sl ^ 1) * 4);
                union { bf16x8 v; bf16 h[8]; } u;
                #pragma unroll
                for (int j = 0; j < 4; ++j) u.h[j] = __float2bfloat16(lo[j]);
                #pragma unroll
                for (int j = 0; j < 4; ++j) u.h[4 + j] = __float2bfloat16(hi[j]);
                af[r] = u.v;
            }
        } else {
            const bf16* As16 = (const bf16*)Asm;
            #pragma unroll
            for (int r = 0; r < 4; ++r) {
                int row = wr * 64 + r * 16 + mi;
                int slot = row * 4 + (q ^ ((row >> 2) & 3));
                af[r] = *(const bf16x8*)(As16 + slot * 8);
            }
        }
        #pragma unroll
        for (int c = 0; c < 4; ++c) {
            int col = wc * 64 + c * 16 + mi;
            int slot = col * 4 + (q ^ ((col >> 2) & 3));
            bfr[c] = *(const bf16x8*)(Bs + slot * 8);
        }
        #pragma unroll
        for (int r = 0; r < 4; ++r)
            #pragma unroll
            for (int c = 0; c < 4; ++c)
                acc[r][c] = __builtin_amdgcn_mfma_f32_16x16x32_bf16(af[r], bfr[c], acc[r][c], 0, 0, 0);
        __syncthreads();
    }

    // epilogue: C/D layout col = lane&15, row = (lane>>4)*4 + i
    #pragma unroll
    for (int r = 0; r < 4; ++r) {
        int rowb = m0 + wr * 64 + r * 16 + q * 4;
        #pragma unroll
        for (int c = 0; c < 4; ++c) {
            int col = n0 + wc * 64 + c * 16 + mi;
            float bv = bias[col];
            #pragma unroll
            for (int i = 0; i < 4; ++i)
                C[(size_t)(rowb + i) * 256 + col] = __float2bfloat16(acc[r][c][i] + bv);
        }
    }
}

// ---------- fused top-of-tree: input 65536 rows (256/tree); 8 levels in-LDS ---
// One block per tree. Hs holds 256 rows x 256 cols bf16 (swizzled 16B chunks).
// 8 waves = 2 row-groups x 4 col-groups, wave 64x64.
__global__ __launch_bounds__(512)
void tree_reduce(const bf16* __restrict__ Hin, const bf16* __restrict__ BT,
                 const float* __restrict__ bias, float* __restrict__ out) {
    __shared__ bf16 Hs[65536];   // 128 KB
    __shared__ bf16 Bs[8192];    // 16 KB

    const int t = threadIdx.x, w = t >> 6, lane = t & 63;
    const int rg = w >> 2, cg = w & 3, mi = lane & 15, q = lane >> 4;
    const int tree = blockIdx.x;
    const bf16* src = Hin + (size_t)tree * 256 * 256;

    // stage the tree's 256 rows; chunk (n, kcd) at slot n*32 + (kcd ^ (n&31))
    #pragma unroll
    for (int i = 0; i < 16; ++i) {
        int s = i * 512 + t;
        int n = s >> 5;
        int kcd = (s & 31) ^ (n & 31);
        async_load16(src + (size_t)n * 256 + kcd * 8, (char*)Hs + i * 8192 + w * 1024);
    }
    __syncthreads();

    for (int Mlev = 128; Mlev >= 1; Mlev >>= 1) {
        bool active = (rg * 64 < Mlev);
        f32x4 acc[4][4] = {};
        for (int k0 = 0; k0 < 512; k0 += 32) {
            // stage B chunk [256 x 32]
            #pragma unroll
            for (int i = 0; i < 2; ++i) {
                int s = i * 512 + t;
                int col = s >> 2;
                int kcd = (s & 3) ^ ((col >> 2) & 3);
                async_load16(BT + (size_t)col * 512 + k0 + kcd * 8,
                             (char*)Bs + i * 8192 + w * 1024);
            }
            __syncthreads();
            if (active) {
                bf16x8 af[4], bfr[4];
                int sel = k0 >> 8;
                int kc = ((k0 & 255) >> 3) + q;
                #pragma unroll
                for (int r = 0; r < 4; ++r) {
                    int n = rg * 64 + r * 16 + mi;          // A row; reads h rows 2n+sel <= 255
                    int hrow = 2 * n + sel;
                    int slot = hrow * 32 + (kc ^ (hrow & 31));
                    af[r] = *(const bf16x8*)(Hs + slot * 8);
                }
                #pragma unroll
                for (int c = 0; c < 4; ++c) {
                    int col = cg * 64 + c * 16 + mi;
                    int slot = col * 4 + (q ^ ((col >> 2) & 3));
                    bfr[c] = *(const bf16x8*)(Bs + slot * 8);
                }
                #pragma unroll
                for (int r = 0; r < 4; ++r)
                    #pragma unroll
                    for (int c = 0; c < 4; ++c)
                        acc[r][c] = __builtin_amdgcn_mfma_f32_16x16x32_bf16(af[r], bfr[c], acc[r][c], 0, 0, 0);
            }
            __syncthreads();
        }
        // writeback
        if (Mlev == 1) {
            if (active && q == 0) {                         // row 0 lives in r=0,q=0,i=0
                #pragma unroll
                for (int c = 0; c < 4; ++c) {
                    int col = cg * 64 + c * 16 + mi;
                    out[(size_t)tree * 256 + col] = acc[0][c][0] + bias[col];
                }
            }
        } else if (active) {
            #pragma unroll
            for (int r = 0; r < 4; ++r) {
                int rowb = rg * 64 + r * 16 + q * 4;
                #pragma unroll
                for (int c = 0; c < 4; ++c) {
                    int col = cg * 64 + c * 16 + mi;
                    float bv = bias[col];
                    int kcc = col >> 3, wb = col & 7;
                    #pragma unroll
                    for (int i = 0; i < 4; ++i) {
                        int n = rowb + i;
                        if (n < Mlev) {
                            int slot = n * 32 + (kcc ^ (n & 31));
                            Hs[slot * 8 + wb] = __float2bfloat16(acc[r][c][i] + bv);
                        }
                    }
                }
            }
        }
        __syncthreads();
    }
}

extern "C" void kernel_launch(void* const* d_in, const int* in_sizes, int n_in,
                              void* d_out, int out_size, void* d_ws, size_t ws_size,
                              hipStream_t stream) {
    const int*   ids = (const int*)d_in[0];
    const float* emb = (const float*)d_in[1];
    const float* W1  = (const float*)d_in[2];
    const float* b1  = (const float*)d_in[3];
    const float* W2  = (const float*)d_in[4];
    const float* b2  = (const float*)d_in[5];
    (void)in_sizes; (void)n_in; (void)out_size; (void)ws_size;

    char* ws = (char*)d_ws;
    size_t off = 0;
    float* zbuf = (float*)(ws + off); off += 256;
    bf16* w1t  = (bf16*)(ws + off); off += (size_t)256 * KP1 * 2;       // 160 KB
    bf16* w2t  = (bf16*)(ws + off); off += (size_t)256 * 512 * 2;       // 256 KB
    bf16* proj = (bf16*)(ws + off); off += (size_t)MP * 256 * 2;        // 25.8 MB
    bf16* h1   = (bf16*)(ws + off); off += (size_t)131072 * 256 * 2;    // 67 MB
    bf16* h2   = (bf16*)(ws + off); off += (size_t)65536 * 256 * 2;     // 33.5 MB
    (void)off;

    // 1) weight transposes/casts + zero scratch
    prep_w<<<832, 256, 0, stream>>>(W1, W2, w1t, w2t, zbuf);

    // 2) projected embedding table (fused fp32 cast): proj = emb @ W1 + b1
    gemm128<2><<<dim3(MP / 128, 2), 256, 0, stream>>>(emb, nullptr, w1t, b1, proj, MP, KP1, zbuf);

    // 3) leaves fused with tree level 0 (gather staged directly from proj):
    //    h1[r] = concat(proj[ids[2r]], proj[ids[2r+1]]) @ W2^T + b2
    gemm128<1><<<dim3(1024, 2), 256, 0, stream>>>(proj, ids, w2t, b2, h1, 131072, 512, nullptr);

    // 4) tree level 1: 131072 rows -> 65536
    gemm128<0><<<dim3(512, 2), 256, 0, stream>>>(h1, nullptr, w2t, b2, h2, 65536, 512, nullptr);

    // 5) levels 2..9 fused in-LDS, one block per tree, fp32 roots to d_out
    tree_reduce<<<256, 512, 0, stream>>>(h2, w2t, b2, (float*)d_out);
}

// Round 3
// 299.013 us; speedup vs baseline: 1.3111x; 1.0853x over previous
//
#include <hip/hip_runtime.h>
#include <hip/hip_bf16.h>
#include <stdint.h>

#define VOCAB 50257
#define WD 300
#define KP1 320              // word dim padded to mult of 32
#define MP 50432             // vocab rows padded: 394*128
#define NLEAF 262144         // 256 trees * 1024 leaves

using bf16 = __hip_bfloat16;
typedef __attribute__((ext_vector_type(4))) float f32x4;
typedef __attribute__((ext_vector_type(8))) short bf16x8;

// async global->LDS, 16B per lane; LDS dest = wave-uniform base + lane*16
__device__ __forceinline__ void async_load16(const void* g, void* l) {
    __builtin_amdgcn_global_load_lds(
        (const __attribute__((address_space(1))) uint32_t*)(uintptr_t)g,
        (__attribute__((address_space(3))) uint32_t*)l, 16, 0, 0);
}

// ---------- prep: w1t = W1^T bf16 [256x320] (zero-pad k>=300)
//                  w2t = W2^T bf16 [256x512]
//                  w2b = W2 cast bf16 [512x256]
//                  b4  = b2@(A+B) + b2 (fp32), zbuf zeros
__global__ void prep_w(const float* __restrict__ W1, const float* __restrict__ W2,
                       const float* __restrict__ b2,
                       bf16* __restrict__ w1t, bf16* __restrict__ w2t,
                       bf16* __restrict__ w2b, float* __restrict__ b4,
                       float* __restrict__ zbuf) {
    if (blockIdx.x == 1344) {           // bias block
        int n = threadIdx.x;
        float acc = b2[n];
        for (int k = 0; k < 256; ++k)
            acc += b2[k] * (W2[k * 256 + n] + W2[(k + 256) * 256 + n]);
        b4[n] = acc;
        if (n < 16) zbuf[n] = 0.0f;
        return;
    }
    int idx = blockIdx.x * 256 + threadIdx.x;
    if (idx < 256 * KP1) {                              // w1t
        int n = idx / KP1;
        int k = idx - n * KP1;
        w1t[idx] = __float2bfloat16(k < WD ? W1[k * 256 + n] : 0.0f);
    } else if (idx < 256 * KP1 + 131072) {              // w2t
        int j = idx - 256 * KP1;
        int n = j >> 8, k = j & 255;                    // [256 x 512]
        // j = n*512 + k form:
        n = j >> 9; k = j & 511;
        w2t[j] = __float2bfloat16(W2[k * 256 + n]);
    } else {                                            // w2b: plain cast
        int j = idx - 256 * KP1 - 131072;
        w2b[j] = __float2bfloat16(W2[j]);
    }
}

// ---------- GEMM: C[M x 256] = A[M x K] @ BT[256 x K]^T + bias ---------------
// AMODE 0: A bf16 row-major, row stride As elems
// AMODE 1: A row r = concat(proj[ids4[r].x..w]), K = 1024 (fused leaf gather)
// AMODE 2: A fp32 rows stride WD (emb), rows clamped to VOCAB-1, zbuf pads
// AMODE 3: W4 products: grid.z = j in 0..3; C_j = Pj^T, Pj = (j&1?B:A)@(j>>1?B:A)
//          A-op = w2t + 256*(j>>1) (stride 512), BT = w2b + 65536*(j&1) (stride 256)
// 128x128 tile, 4 waves (2x2), wave 64x64 via 4x4 mfma 16x16x32 bf16.
template <int AMODE, bool OUT_F32>
__global__ __launch_bounds__(256)
void gemm128(const void* __restrict__ Av, const int* __restrict__ ids,
             const bf16* __restrict__ BT, const float* __restrict__ bias,
             void* __restrict__ C, int M, int K, int As, int Bstr, int Cs,
             const float* __restrict__ zbuf) {
    constexpr int ABYTES = (AMODE == 2) ? 16384 : 8192;
    __shared__ char smem[ABYTES + 8192];
    char* Asm = smem;
    bf16* Bsm = (bf16*)(smem + ABYTES);

    const int t = threadIdx.x, w = t >> 6, lane = t & 63;
    const int wr = w >> 1, wc = w & 1, mi = lane & 15, q = lane >> 4;
    const int m0 = blockIdx.x * 128, n0 = blockIdx.y * 128;

    const bf16* Ab = (const bf16*)Av;
    int coff = 0;
    if constexpr (AMODE == 3) {
        int j = blockIdx.z;
        Ab = (const bf16*)Av + 256 * (j >> 1);
        BT = BT + 65536 * (j & 1);
        coff = 256 * j;
    }

    int4 idq0 = {0,0,0,0}, idq1 = {0,0,0,0};
    if constexpr (AMODE == 1) {
        idq0 = ((const int4*)ids)[m0 + (t >> 2)];
        idq1 = ((const int4*)ids)[m0 + 64 + (t >> 2)];
    }

    f32x4 acc[4][4] = {};

    for (int k0 = 0; k0 < K; k0 += 32) {
        // ---- stage A tile ----
        if constexpr (AMODE == 2) {
            const float* A32 = (const float*)Av;
            #pragma unroll
            for (int i = 0; i < 4; ++i) {
                int s = i * 256 + t;
                int row = s >> 3;
                int kcd = (s & 7) ^ (row & 7);
                int k = k0 + kcd * 4;
                int grow = m0 + row; if (grow >= VOCAB) grow = VOCAB - 1;
                const float* g = (k <= 296) ? (A32 + (size_t)grow * WD + k) : zbuf;
                async_load16(g, Asm + i * 4096 + w * 1024);
            }
        } else {
            #pragma unroll
            for (int i = 0; i < 2; ++i) {
                int s = i * 256 + t;
                int row = s >> 2;
                int kcd = (s & 3) ^ ((row >> 2) & 3);
                const bf16* g;
                if constexpr (AMODE == 1) {
                    int sel = k0 >> 8;                       // which leaf slot (uniform)
                    const int4& qd = (i == 0) ? idq0 : idq1;
                    int id = (sel & 2) ? ((sel & 1) ? qd.w : qd.z)
                                       : ((sel & 1) ? qd.y : qd.x);
                    g = (const bf16*)Av + (size_t)id * 256 + (k0 & 255) + kcd * 8;
                } else {
                    g = Ab + (size_t)(m0 + row) * As + k0 + kcd * 8;
                }
                async_load16(g, Asm + i * 4096 + w * 1024);
            }
        }
        // ---- stage B tile (128 cols x 32 k) ----
        #pragma unroll
        for (int i = 0; i < 2; ++i) {
            int s = i * 256 + t;
            int col = s >> 2;
            int kcd = (s & 3) ^ ((col >> 2) & 3);
            async_load16(BT + (size_t)(n0 + col) * Bstr + k0 + kcd * 8,
                         (char*)Bsm + i * 4096 + w * 1024);
        }
        __syncthreads();

        // ---- fragments ----
        bf16x8 af[4], bfr[4];
        if constexpr (AMODE == 2) {
            const float* As32 = (const float*)Asm;
            #pragma unroll
            for (int r = 0; r < 4; ++r) {
                int row = wr * 64 + r * 16 + mi;
                int sl = row * 8 + ((2 * q) ^ (row & 7));
                f32x4 lo = *(const f32x4*)(As32 + sl * 4);
                f32x4 hi = *(const f32x4*)(As32 + (sl ^ 1) * 4);
                union { bf16x8 v; bf16 h[8]; } u;
                #pragma unroll
                for (int j = 0; j < 4; ++j) u.h[j] = __float2bfloat16(lo[j]);
                #pragma unroll
                for (int j = 0; j < 4; ++j) u.h[4 + j] = __float2bfloat16(hi[j]);
                af[r] = u.v;
            }
        } else {
            const bf16* As16 = (const bf16*)Asm;
            #pragma unroll
            for (int r = 0; r < 4; ++r) {
                int row = wr * 64 + r * 16 + mi;
                int slot = row * 4 + (q ^ ((row >> 2) & 3));
                af[r] = *(const bf16x8*)(As16 + slot * 8);
            }
        }
        #pragma unroll
        for (int c = 0; c < 4; ++c) {
            int col = wc * 64 + c * 16 + mi;
            int slot = col * 4 + (q ^ ((col >> 2) & 3));
            bfr[c] = *(const bf16x8*)(Bsm + slot * 8);
        }
        #pragma unroll
        for (int r = 0; r < 4; ++r)
            #pragma unroll
            for (int c = 0; c < 4; ++c)
                acc[r][c] = __builtin_amdgcn_mfma_f32_16x16x32_bf16(af[r], bfr[c], acc[r][c], 0, 0, 0);
        __syncthreads();
    }

    // epilogue: C/D layout col = lane&15, row = (lane>>4)*4 + i
    #pragma unroll
    for (int r = 0; r < 4; ++r) {
        int rowb = m0 + wr * 64 + r * 16 + q * 4;
        #pragma unroll
        for (int c = 0; c < 4; ++c) {
            int col = n0 + wc * 64 + c * 16 + mi;
            float bv = (AMODE == 3) ? 0.0f : bias[col];
            #pragma unroll
            for (int i = 0; i < 4; ++i) {
                float v = acc[r][c][i] + bv;
                size_t o = (size_t)(rowb + i) * Cs + coff + col;
                if (OUT_F32) ((float*)C)[o] = v;
                else         ((bf16*)C)[o] = __float2bfloat16(v);
            }
        }
    }
}

extern "C" void kernel_launch(void* const* d_in, const int* in_sizes, int n_in,
                              void* d_out, int out_size, void* d_ws, size_t ws_size,
                              hipStream_t stream) {
    const int*   ids = (const int*)d_in[0];
    const float* emb = (const float*)d_in[1];
    const float* W1  = (const float*)d_in[2];
    const float* b1  = (const float*)d_in[3];
    const float* W2  = (const float*)d_in[4];
    const float* b2  = (const float*)d_in[5];
    (void)in_sizes; (void)n_in; (void)out_size; (void)ws_size;

    char* ws = (char*)d_ws;
    size_t off = 0;
    float* zbuf = (float*)(ws + off); off += 1024;
    float* b4   = (float*)(ws + off); off += 1024;
    bf16* w1t = (bf16*)(ws + off); off += (size_t)256 * KP1 * 2;     // 160 KB
    bf16* w2t = (bf16*)(ws + off); off += (size_t)256 * 512 * 2;     // 256 KB
    bf16* w2b = (bf16*)(ws + off); off += (size_t)512 * 256 * 2;     // 256 KB
    bf16* w4t = (bf16*)(ws + off); off += (size_t)256 * 1024 * 2;    // 512 KB
    bf16* proj = (bf16*)(ws + off); off += (size_t)MP * 256 * 2;     // 25.8 MB
    bf16* h  = (bf16*)(ws + off); off += (size_t)65536 * 256 * 2;    // 33.5 MB
    bf16* t1 = (bf16*)(ws + off); off += (size_t)16384 * 256 * 2;    // 8.4 MB
    bf16* t2 = (bf16*)(ws + off); off += (size_t)4096 * 256 * 2;     // 2.1 MB
    bf16* t3 = (bf16*)(ws + off); off += (size_t)1024 * 256 * 2;     // 0.5 MB
    (void)off;

    // 1) weight casts/transposes + b4 + zeros  (1345 blocks; block 1344 = bias)
    prep_w<<<1345, 256, 0, stream>>>(W1, W2, b2, w1t, w2t, w2b, b4, zbuf);

    // 2) W4T products: C_j = Pj^T  (j = grid.z)
    gemm128<3, false><<<dim3(2, 2, 4), 256, 0, stream>>>(
        w2t, nullptr, w2b, nullptr, w4t, 256, 256, 512, 256, 1024, nullptr);

    // 3) projected embedding table: proj = emb @ W1 + b1  [MP x 256]
    gemm128<2, false><<<dim3(MP / 128, 2), 256, 0, stream>>>(
        emb, nullptr, w1t, b1, proj, MP, KP1, WD, KP1, 256, zbuf);

    // 4) main: leaves + levels 0-1 fused: h[r] = concat4(proj[ids4[r]]) @ W4 + b4
    gemm128<1, false><<<dim3(512, 2), 256, 0, stream>>>(
        proj, ids, w4t, b4, h, 65536, 1024, 256, 1024, 256, nullptr);

    // 5) tail: W4 steps (input viewed [M/4 x 1024], contiguous)
    gemm128<0, false><<<dim3(128, 2), 256, 0, stream>>>(
        h, nullptr, w4t, b4, t1, 16384, 1024, 1024, 1024, 256, nullptr);
    gemm128<0, false><<<dim3(32, 2), 256, 0, stream>>>(
        t1, nullptr, w4t, b4, t2, 4096, 1024, 1024, 1024, 256, nullptr);
    gemm128<0, false><<<dim3(8, 2), 256, 0, stream>>>(
        t2, nullptr, w4t, b4, t3, 1024, 1024, 1024, 1024, 256, nullptr);
    gemm128<0, true><<<dim3(2, 2), 256, 0, stream>>>(
        t3, nullptr, w4t, b4, d_out, 256, 1024, 1024, 1024, 256, nullptr);
}

// Round 4
// 283.261 us; speedup vs baseline: 1.3840x; 1.0556x over previous
//
#include <hip/hip_runtime.h>
#include <hip/hip_bf16.h>
#include <stdint.h>

#define VOCAB 50257
#define WD 300
#define KP1 320              // word dim padded to mult of 32
#define MP 50432             // vocab rows padded: 394*128

using bf16 = __hip_bfloat16;
typedef __attribute__((ext_vector_type(4))) float f32x4;
typedef __attribute__((ext_vector_type(8))) short bf16x8;

// async global->LDS, 16B per lane; LDS dest = wave-uniform base + lane*16
__device__ __forceinline__ void async_load16(const void* g, void* l) {
    __builtin_amdgcn_global_load_lds(
        (const __attribute__((address_space(1))) uint32_t*)(uintptr_t)g,
        (__attribute__((address_space(3))) uint32_t*)l, 16, 0, 0);
}

// ---------- prep: w1t = W1^T bf16 [256x320] (zero-pad k>=300)
//                  w2t = W2^T bf16 [256x512]
//                  w2b = W2 cast bf16 [512x256]
//                  b4  = b2@(A+B) + b2 (fp32), zbuf zeros
__global__ void prep_w(const float* __restrict__ W1, const float* __restrict__ W2,
                       const float* __restrict__ b2,
                       bf16* __restrict__ w1t, bf16* __restrict__ w2t,
                       bf16* __restrict__ w2b, float* __restrict__ b4,
                       float* __restrict__ zbuf) {
    if (blockIdx.x == 1344) {           // bias block
        int n = threadIdx.x;
        float acc = b2[n];
        for (int k = 0; k < 256; ++k)
            acc += b2[k] * (W2[k * 256 + n] + W2[(k + 256) * 256 + n]);
        b4[n] = acc;
        if (n < 16) zbuf[n] = 0.0f;
        return;
    }
    int idx = blockIdx.x * 256 + threadIdx.x;
    if (idx < 256 * KP1) {                              // w1t
        int n = idx / KP1;
        int k = idx - n * KP1;
        w1t[idx] = __float2bfloat16(k < WD ? W1[k * 256 + n] : 0.0f);
    } else if (idx < 256 * KP1 + 131072) {              // w2t
        int j = idx - 256 * KP1;
        int n = j >> 9, k = j & 511;
        w2t[j] = __float2bfloat16(W2[k * 256 + n]);
    } else {                                            // w2b: plain cast
        int j = idx - 256 * KP1 - 131072;
        w2b[j] = __float2bfloat16(W2[j]);
    }
}

// ---------- GEMM: C[M x 256] = A[M x K] @ BT[256 x K]^T + bias ---------------
// AMODE 0: A bf16 row-major, row stride As elems
// AMODE 1: A row r = concat(proj[ids4[r].x..w]), K = 1024 (fused leaf gather)
// AMODE 2: A fp32 rows stride WD (emb), rows clamped to VOCAB-1, zbuf pads
// AMODE 3: W4 products: grid.z = j; A-op = w2t + 256*(j>>1), BT = w2b + 65536*(j&1)
// 128x128 tile, 4 waves (2x2), wave 64x64 via 4x4 mfma 16x16x32 bf16.
// 3-stage LDS pipeline: wait vmcnt(n_inflight_next) -> s_barrier -> issue k+2
// -> compute k. Avoids the compiler's full vmcnt(0) barrier drain.
template <int AMODE, bool OUT_F32>
__global__ __launch_bounds__(256)
void gemm128(const void* __restrict__ Av, const int* __restrict__ ids,
             const bf16* __restrict__ BT, const float* __restrict__ bias,
             void* __restrict__ C, int M, int K, int As, int Bstr, int Cs,
             const float* __restrict__ zbuf) {
    constexpr int ABYTES = (AMODE == 2) ? 16384 : 8192;
    constexpr int STAGE  = ABYTES + 8192;
    __shared__ char smem[3 * STAGE];

    const int t = threadIdx.x, w = t >> 6, lane = t & 63;
    const int wr = w >> 1, wc = w & 1, mi = lane & 15, q = lane >> 4;
    const int m0 = blockIdx.x * 128, n0 = blockIdx.y * 128;

    const bf16* Ab = (const bf16*)Av;
    const bf16* BTp = BT;
    int coff = 0;
    if constexpr (AMODE == 3) {
        int j = blockIdx.z;
        Ab = (const bf16*)Av + 256 * (j >> 1);
        BTp = BT + 65536 * (j & 1);
        coff = 256 * j;
    }

    int4 idq0 = {0,0,0,0}, idq1 = {0,0,0,0};
    if constexpr (AMODE == 1) {
        idq0 = ((const int4*)ids)[m0 + (t >> 2)];
        idq1 = ((const int4*)ids)[m0 + 64 + (t >> 2)];
    }

    // stage one 32-wide K chunk (elements [ke, ke+32)) into buffer `buf`
    auto stage = [&](int ke, int buf) {
        char* Asm = smem + buf * STAGE;
        char* Bsm = Asm + ABYTES;
        if constexpr (AMODE == 2) {
            const float* A32 = (const float*)Av;
            #pragma unroll
            for (int i = 0; i < 4; ++i) {
                int s = i * 256 + t;
                int row = s >> 3;
                int kcd = (s & 7) ^ (row & 7);
                int k = ke + kcd * 4;
                int grow = m0 + row; if (grow >= VOCAB) grow = VOCAB - 1;
                const float* g = (k <= 296) ? (A32 + (size_t)grow * WD + k) : zbuf;
                async_load16(g, Asm + i * 4096 + w * 1024);
            }
        } else {
            #pragma unroll
            for (int i = 0; i < 2; ++i) {
                int s = i * 256 + t;
                int row = s >> 2;
                int kcd = (s & 3) ^ ((row >> 2) & 3);
                const bf16* g;
                if constexpr (AMODE == 1) {
                    int sel = ke >> 8;                     // leaf slot (wave-uniform)
                    const int4& qd = (i == 0) ? idq0 : idq1;
                    int id = (sel & 2) ? ((sel & 1) ? qd.w : qd.z)
                                       : ((sel & 1) ? qd.y : qd.x);
                    g = (const bf16*)Av + (size_t)id * 256 + (ke & 255) + kcd * 8;
                } else {
                    g = Ab + (size_t)(m0 + row) * As + ke + kcd * 8;
                }
                async_load16(g, Asm + i * 4096 + w * 1024);
            }
        }
        #pragma unroll
        for (int i = 0; i < 2; ++i) {
            int s = i * 256 + t;
            int col = s >> 2;
            int kcd = (s & 3) ^ ((col >> 2) & 3);
            async_load16(BTp + (size_t)(n0 + col) * Bstr + ke + kcd * 8,
                         (char*)Bsm + i * 4096 + w * 1024);
        }
    };

    f32x4 acc[4][4] = {};
    const int S = K >> 5;

    stage(0, 0);
    if (S > 1) stage(32, 1);

    for (int k0 = 0; k0 < S; ++k0) {
        // wait: stage(k0) complete (leave stage(k0+1)'s loads in flight), then barrier
        if (k0 + 1 < S) {
            if constexpr (AMODE == 2)
                asm volatile("s_waitcnt vmcnt(6)\n\ts_barrier" ::: "memory");
            else
                asm volatile("s_waitcnt vmcnt(4)\n\ts_barrier" ::: "memory");
        } else {
            asm volatile("s_waitcnt vmcnt(0)\n\ts_barrier" ::: "memory");
        }
        // issue stage k0+2 into the buffer freed by the barrier above
        if (k0 + 2 < S) stage((k0 + 2) * 32, (k0 + 2) % 3);

        const char* Asm = smem + (k0 % 3) * STAGE;
        const bf16* Bsm = (const bf16*)(Asm + ABYTES);

        bf16x8 af[4], bfr[4];
        if constexpr (AMODE == 2) {
            const float* As32 = (const float*)Asm;
            #pragma unroll
            for (int r = 0; r < 4; ++r) {
                int row = wr * 64 + r * 16 + mi;
                int sl = row * 8 + ((2 * q) ^ (row & 7));
                f32x4 lo = *(const f32x4*)(As32 + sl * 4);
                f32x4 hi = *(const f32x4*)(As32 + (sl ^ 1) * 4);
                union { bf16x8 v; bf16 h[8]; } u;
                #pragma unroll
                for (int j = 0; j < 4; ++j) u.h[j] = __float2bfloat16(lo[j]);
                #pragma unroll
                for (int j = 0; j < 4; ++j) u.h[4 + j] = __float2bfloat16(hi[j]);
                af[r] = u.v;
            }
        } else {
            const bf16* As16 = (const bf16*)Asm;
            #pragma unroll
            for (int r = 0; r < 4; ++r) {
                int row = wr * 64 + r * 16 + mi;
                int slot = row * 4 + (q ^ ((row >> 2) & 3));
                af[r] = *(const bf16x8*)(As16 + slot * 8);
            }
        }
        #pragma unroll
        for (int c = 0; c < 4; ++c) {
            int col = wc * 64 + c * 16 + mi;
            int slot = col * 4 + (q ^ ((col >> 2) & 3));
            bfr[c] = *(const bf16x8*)(Bsm + slot * 8);
        }
        #pragma unroll
        for (int r = 0; r < 4; ++r)
            #pragma unroll
            for (int c = 0; c < 4; ++c)
                acc[r][c] = __builtin_amdgcn_mfma_f32_16x16x32_bf16(af[r], bfr[c], acc[r][c], 0, 0, 0);
    }

    // epilogue: C/D layout col = lane&15, row = (lane>>4)*4 + i
    #pragma unroll
    for (int r = 0; r < 4; ++r) {
        int rowb = m0 + wr * 64 + r * 16 + q * 4;
        #pragma unroll
        for (int c = 0; c < 4; ++c) {
            int col = n0 + wc * 64 + c * 16 + mi;
            float bv = (AMODE == 3) ? 0.0f : bias[col];
            #pragma unroll
            for (int i = 0; i < 4; ++i) {
                float v = acc[r][c][i] + bv;
                size_t o = (size_t)(rowb + i) * Cs + coff + col;
                if (OUT_F32) ((float*)C)[o] = v;
                else         ((bf16*)C)[o] = __float2bfloat16(v);
            }
        }
    }
}

extern "C" void kernel_launch(void* const* d_in, const int* in_sizes, int n_in,
                              void* d_out, int out_size, void* d_ws, size_t ws_size,
                              hipStream_t stream) {
    const int*   ids = (const int*)d_in[0];
    const float* emb = (const float*)d_in[1];
    const float* W1  = (const float*)d_in[2];
    const float* b1  = (const float*)d_in[3];
    const float* W2  = (const float*)d_in[4];
    const float* b2  = (const float*)d_in[5];
    (void)in_sizes; (void)n_in; (void)out_size; (void)ws_size;

    char* ws = (char*)d_ws;
    size_t off = 0;
    float* zbuf = (float*)(ws + off); off += 1024;
    float* b4   = (float*)(ws + off); off += 1024;
    bf16* w1t = (bf16*)(ws + off); off += (size_t)256 * KP1 * 2;     // 160 KB
    bf16* w2t = (bf16*)(ws + off); off += (size_t)256 * 512 * 2;     // 256 KB
    bf16* w2b = (bf16*)(ws + off); off += (size_t)512 * 256 * 2;     // 256 KB
    bf16* w4t = (bf16*)(ws + off); off += (size_t)256 * 1024 * 2;    // 512 KB
    bf16* proj = (bf16*)(ws + off); off += (size_t)MP * 256 * 2;     // 25.8 MB
    bf16* h  = (bf16*)(ws + off); off += (size_t)65536 * 256 * 2;    // 33.5 MB
    bf16* t1 = (bf16*)(ws + off); off += (size_t)16384 * 256 * 2;    // 8.4 MB
    bf16* t2 = (bf16*)(ws + off); off += (size_t)4096 * 256 * 2;     // 2.1 MB
    bf16* t3 = (bf16*)(ws + off); off += (size_t)1024 * 256 * 2;     // 0.5 MB
    (void)off;

    // 1) weight casts/transposes + b4 + zeros
    prep_w<<<1345, 256, 0, stream>>>(W1, W2, b2, w1t, w2t, w2b, b4, zbuf);

    // 2) W4T products
    gemm128<3, false><<<dim3(2, 2, 4), 256, 0, stream>>>(
        w2t, nullptr, w2b, nullptr, w4t, 256, 256, 512, 256, 1024, nullptr);

    // 3) projected embedding table: proj = emb @ W1 + b1  [MP x 256]
    gemm128<2, false><<<dim3(MP / 128, 2), 256, 0, stream>>>(
        emb, nullptr, w1t, b1, proj, MP, KP1, WD, KP1, 256, zbuf);

    // 4) main: leaves + levels 0-1 fused: h[r] = concat4(proj[ids4[r]]) @ W4 + b4
    gemm128<1, false><<<dim3(512, 2), 256, 0, stream>>>(
        proj, ids, w4t, b4, h, 65536, 1024, 256, 1024, 256, nullptr);

    // 5) tail: W4 steps (input viewed [M/4 x 1024], contiguous)
    gemm128<0, false><<<dim3(128, 2), 256, 0, stream>>>(
        h, nullptr, w4t, b4, t1, 16384, 1024, 1024, 1024, 256, nullptr);
    gemm128<0, false><<<dim3(32, 2), 256, 0, stream>>>(
        t1, nullptr, w4t, b4, t2, 4096, 1024, 1024, 1024, 256, nullptr);
    gemm128<0, false><<<dim3(8, 2), 256, 0, stream>>>(
        t2, nullptr, w4t, b4, t3, 1024, 1024, 1024, 1024, 256, nullptr);
    gemm128<0, true><<<dim3(2, 2), 256, 0, stream>>>(
        t3, nullptr, w4t, b4, d_out, 256, 1024, 1024, 1024, 256, nullptr);
}

// Round 5
// 266.159 us; speedup vs baseline: 1.4729x; 1.0643x over previous
//
#include <hip/hip_runtime.h>
#include <hip/hip_bf16.h>
#include <stdint.h>

#define VOCAB 50257
#define WD 300
#define KP1 320              // word dim padded to mult of 32
#define MP 50432             // vocab rows padded: 394*128

using bf16 = __hip_bfloat16;
typedef __attribute__((ext_vector_type(4))) float f32x4;
typedef __attribute__((ext_vector_type(8))) short bf16x8;

// async global->LDS, 16B per lane; LDS dest = wave-uniform base + lane*16
__device__ __forceinline__ void async_load16(const void* g, void* l) {
    __builtin_amdgcn_global_load_lds(
        (const __attribute__((address_space(1))) uint32_t*)(uintptr_t)g,
        (__attribute__((address_space(3))) uint32_t*)l, 16, 0, 0);
}

// ---------- prep: w1t = W1^T bf16 [256x320]; w2t = W2^T bf16 [256x512];
//                  w2b = W2 cast bf16 [512x256]; b4 = b2@(A+B)+b2; zbuf zeros
__global__ void prep_w(const float* __restrict__ W1, const float* __restrict__ W2,
                       const float* __restrict__ b2,
                       bf16* __restrict__ w1t, bf16* __restrict__ w2t,
                       bf16* __restrict__ w2b, float* __restrict__ b4,
                       float* __restrict__ zbuf) {
    if (blockIdx.x == 1344) {           // bias block
        int n = threadIdx.x;
        float acc = b2[n];
        for (int k = 0; k < 256; ++k)
            acc += b2[k] * (W2[k * 256 + n] + W2[(k + 256) * 256 + n]);
        b4[n] = acc;
        if (n < 16) zbuf[n] = 0.0f;
        return;
    }
    int idx = blockIdx.x * 256 + threadIdx.x;
    if (idx < 256 * KP1) {                              // w1t
        int n = idx / KP1;
        int k = idx - n * KP1;
        w1t[idx] = __float2bfloat16(k < WD ? W1[k * 256 + n] : 0.0f);
    } else if (idx < 256 * KP1 + 131072) {              // w2t
        int j = idx - 256 * KP1;
        int n = j >> 9, k = j & 511;
        w2t[j] = __float2bfloat16(W2[k * 256 + n]);
    } else {                                            // w2b: plain cast
        int j = idx - 256 * KP1 - 131072;
        w2b[j] = __float2bfloat16(W2[j]);
    }
}

// ---------- gemm128: 128x128 tile, 4 waves, m97 2-barrier (proj + W4T) -------
// AMODE 2: A fp32 emb rows (stride WD, rows clamped), K = KP1
// AMODE 3: W4 products: grid.z = j; A-op = w2t + 256*(j>>1), BT = w2b + 65536*(j&1)
template <int AMODE, bool OUT_F32>
__global__ __launch_bounds__(256)
void gemm128(const void* __restrict__ Av, const bf16* __restrict__ BT,
             const float* __restrict__ bias, void* __restrict__ C,
             int M, int K, int As, int Bstr, int Cs,
             const float* __restrict__ zbuf) {
    constexpr int ABYTES = (AMODE == 2) ? 16384 : 8192;
    __shared__ char smem[ABYTES + 8192];
    char* Asm = smem;
    bf16* Bsm = (bf16*)(smem + ABYTES);

    const int t = threadIdx.x, w = t >> 6, lane = t & 63;
    const int wr = w >> 1, wc = w & 1, mi = lane & 15, q = lane >> 4;
    const int m0 = blockIdx.x * 128, n0 = blockIdx.y * 128;

    const bf16* Ab = (const bf16*)Av;
    const bf16* BTp = BT;
    int coff = 0;
    if constexpr (AMODE == 3) {
        int j = blockIdx.z;
        Ab = (const bf16*)Av + 256 * (j >> 1);
        BTp = BT + 65536 * (j & 1);
        coff = 256 * j;
    }

    f32x4 acc[4][4] = {};

    for (int k0 = 0; k0 < K; k0 += 32) {
        if constexpr (AMODE == 2) {
            const float* A32 = (const float*)Av;
            #pragma unroll
            for (int i = 0; i < 4; ++i) {
                int s = i * 256 + t;
                int row = s >> 3;
                int kcd = (s & 7) ^ (row & 7);
                int k = k0 + kcd * 4;
                int grow = m0 + row; if (grow >= VOCAB) grow = VOCAB - 1;
                const float* g = (k <= 296) ? (A32 + (size_t)grow * WD + k) : zbuf;
                async_load16(g, Asm + i * 4096 + w * 1024);
            }
        } else {
            #pragma unroll
            for (int i = 0; i < 2; ++i) {
                int s = i * 256 + t;
                int row = s >> 2;
                int kcd = (s & 3) ^ ((row >> 2) & 3);
                async_load16(Ab + (size_t)(m0 + row) * As + k0 + kcd * 8,
                             Asm + i * 4096 + w * 1024);
            }
        }
        #pragma unroll
        for (int i = 0; i < 2; ++i) {
            int s = i * 256 + t;
            int col = s >> 2;
            int kcd = (s & 3) ^ ((col >> 2) & 3);
            async_load16(BTp + (size_t)(n0 + col) * Bstr + k0 + kcd * 8,
                         (char*)Bsm + i * 4096 + w * 1024);
        }
        __syncthreads();

        bf16x8 af[4], bfr[4];
        if constexpr (AMODE == 2) {
            const float* As32 = (const float*)Asm;
            #pragma unroll
            for (int r = 0; r < 4; ++r) {
                int row = wr * 64 + r * 16 + mi;
                int sl = row * 8 + ((2 * q) ^ (row & 7));
                f32x4 lo = *(const f32x4*)(As32 + sl * 4);
                f32x4 hi = *(const f32x4*)(As32 + (sl ^ 1) * 4);
                union { bf16x8 v; bf16 h[8]; } u;
                #pragma unroll
                for (int j = 0; j < 4; ++j) u.h[j] = __float2bfloat16(lo[j]);
                #pragma unroll
                for (int j = 0; j < 4; ++j) u.h[4 + j] = __float2bfloat16(hi[j]);
                af[r] = u.v;
            }
        } else {
            const bf16* As16 = (const bf16*)Asm;
            #pragma unroll
            for (int r = 0; r < 4; ++r) {
                int row = wr * 64 + r * 16 + mi;
                int slot = row * 4 + (q ^ ((row >> 2) & 3));
                af[r] = *(const bf16x8*)(As16 + slot * 8);
            }
        }
        #pragma unroll
        for (int c = 0; c < 4; ++c) {
            int col = wc * 64 + c * 16 + mi;
            int slot = col * 4 + (q ^ ((col >> 2) & 3));
            bfr[c] = *(const bf16x8*)(Bsm + slot * 8);
        }
        #pragma unroll
        for (int r = 0; r < 4; ++r)
            #pragma unroll
            for (int c = 0; c < 4; ++c)
                acc[r][c] = __builtin_amdgcn_mfma_f32_16x16x32_bf16(af[r], bfr[c], acc[r][c], 0, 0, 0);
        __syncthreads();
    }

    #pragma unroll
    for (int r = 0; r < 4; ++r) {
        int rowb = m0 + wr * 64 + r * 16 + q * 4;
        #pragma unroll
        for (int c = 0; c < 4; ++c) {
            int col = n0 + wc * 64 + c * 16 + mi;
            float bv = (AMODE == 3) ? 0.0f : bias[col];
            #pragma unroll
            for (int i = 0; i < 4; ++i) {
                float v = acc[r][c][i] + bv;
                size_t o = (size_t)(rowb + i) * Cs + coff + col;
                if (OUT_F32) ((float*)C)[o] = v;
                else         ((bf16*)C)[o] = __float2bfloat16(v);
            }
        }
    }
}

// ---------- gemm512: 128-row x FULL-256-col tile, 8 waves (2 rg x 4 cg) ------
// AMODE 1: A row r = concat4(proj[ids4[m0+r]]), K = 1024 (fused leaf gather)
// AMODE 0: A bf16 [M x K] contiguous (tail W4 steps)
// PIPE: 3-stage LDS pipeline w/ fine vmcnt (use only on small grids);
// else m97 2-barrier single stage.
template <int AMODE, bool PIPE, bool OUT_F32>
__global__ __launch_bounds__(512)
void gemm512(const void* __restrict__ Av, const int* __restrict__ ids,
             const bf16* __restrict__ BT, const float* __restrict__ bias,
             void* __restrict__ C, int K) {
    constexpr int ASZ = 8192, BSZ = 16384, STAGE = ASZ + BSZ;
    __shared__ char smem[PIPE ? 3 * STAGE : STAGE];

    const int t = threadIdx.x, w = t >> 6, lane = t & 63;
    const int rg = w >> 2, cg = w & 3, mi = lane & 15, q = lane >> 4;
    const int m0 = blockIdx.x * 128;
    const bf16* Ab = (const bf16*)Av;

    int4 idq = {0, 0, 0, 0};
    if constexpr (AMODE == 1) idq = ((const int4*)ids)[m0 + (t >> 2)];

    auto stage = [&](int ke, int buf) {
        char* Asm = smem + buf * STAGE;
        char* Bsm = Asm + ASZ;
        {   // A: 512 chunks of 16B, 1 per thread
            int row = t >> 2;
            int kcd = (t & 3) ^ ((row >> 2) & 3);
            const bf16* g;
            if constexpr (AMODE == 1) {
                int sel = ke >> 8;                      // leaf slot, wave-uniform
                int id = (sel & 2) ? ((sel & 1) ? idq.w : idq.z)
                                   : ((sel & 1) ? idq.y : idq.x);
                g = Ab + (size_t)id * 256 + (ke & 255) + kcd * 8;
            } else {
                g = Ab + (size_t)(m0 + row) * K + ke + kcd * 8;
            }
            async_load16(g, Asm + w * 1024);
        }
        #pragma unroll
        for (int i = 0; i < 2; ++i) {                   // B: 1024 chunks, 2/thread
            int s = i * 512 + t;
            int col = s >> 2;
            int kcd = (s & 3) ^ ((col >> 2) & 3);
            async_load16(BT + (size_t)col * K + ke + kcd * 8,
                         Bsm + i * 8192 + w * 1024);
        }
    };

    f32x4 acc[4][4] = {};

    auto compute = [&](int buf) {
        const bf16* As16 = (const bf16*)(smem + buf * STAGE);
        const bf16* Bs16 = (const bf16*)(smem + buf * STAGE + ASZ);
        bf16x8 af[4], bfr[4];
        #pragma unroll
        for (int r = 0; r < 4; ++r) {
            int row = rg * 64 + r * 16 + mi;
            int slot = row * 4 + (q ^ ((row >> 2) & 3));
            af[r] = *(const bf16x8*)(As16 + slot * 8);
        }
        #pragma unroll
        for (int c = 0; c < 4; ++c) {
            int col = cg * 64 + c * 16 + mi;
            int slot = col * 4 + (q ^ ((col >> 2) & 3));
            bfr[c] = *(const bf16x8*)(Bs16 + slot * 8);
        }
        #pragma unroll
        for (int r = 0; r < 4; ++r)
            #pragma unroll
            for (int c = 0; c < 4; ++c)
                acc[r][c] = __builtin_amdgcn_mfma_f32_16x16x32_bf16(af[r], bfr[c], acc[r][c], 0, 0, 0);
    };

    const int S = K >> 5;
    if constexpr (!PIPE) {
        for (int k0 = 0; k0 < S; ++k0) {
            stage(k0 * 32, 0);
            __syncthreads();
            compute(0);
            __syncthreads();
        }
    } else {
        stage(0, 0);
        if (S > 1) stage(32, 1);
        for (int k0 = 0; k0 < S; ++k0) {
            if (k0 + 1 < S)
                asm volatile("s_waitcnt vmcnt(3)\n\ts_barrier" ::: "memory");
            else
                asm volatile("s_waitcnt vmcnt(0)\n\ts_barrier" ::: "memory");
            if (k0 + 2 < S) stage((k0 + 2) * 32, (k0 + 2) % 3);
            compute(k0 % 3);
        }
    }

    // epilogue: C/D layout col = lane&15, row = (lane>>4)*4 + i
    #pragma unroll
    for (int r = 0; r < 4; ++r) {
        int rowb = m0 + rg * 64 + r * 16 + q * 4;
        #pragma unroll
        for (int c = 0; c < 4; ++c) {
            int col = cg * 64 + c * 16 + mi;
            float bv = bias[col];
            #pragma unroll
            for (int i = 0; i < 4; ++i) {
                float v = acc[r][c][i] + bv;
                size_t o = (size_t)(rowb + i) * 256 + col;
                if (OUT_F32) ((float*)C)[o] = v;
                else         ((bf16*)C)[o] = __float2bfloat16(v);
            }
        }
    }
}

extern "C" void kernel_launch(void* const* d_in, const int* in_sizes, int n_in,
                              void* d_out, int out_size, void* d_ws, size_t ws_size,
                              hipStream_t stream) {
    const int*   ids = (const int*)d_in[0];
    const float* emb = (const float*)d_in[1];
    const float* W1  = (const float*)d_in[2];
    const float* b1  = (const float*)d_in[3];
    const float* W2  = (const float*)d_in[4];
    const float* b2  = (const float*)d_in[5];
    (void)in_sizes; (void)n_in; (void)out_size; (void)ws_size;

    char* ws = (char*)d_ws;
    size_t off = 0;
    float* zbuf = (float*)(ws + off); off += 1024;
    float* b4   = (float*)(ws + off); off += 1024;
    bf16* w1t = (bf16*)(ws + off); off += (size_t)256 * KP1 * 2;     // 160 KB
    bf16* w2t = (bf16*)(ws + off); off += (size_t)256 * 512 * 2;     // 256 KB
    bf16* w2b = (bf16*)(ws + off); off += (size_t)512 * 256 * 2;     // 256 KB
    bf16* w4t = (bf16*)(ws + off); off += (size_t)256 * 1024 * 2;    // 512 KB
    bf16* proj = (bf16*)(ws + off); off += (size_t)MP * 256 * 2;     // 25.8 MB
    bf16* h  = (bf16*)(ws + off); off += (size_t)65536 * 256 * 2;    // 33.5 MB
    bf16* t1 = (bf16*)(ws + off); off += (size_t)16384 * 256 * 2;    // 8.4 MB
    bf16* t2 = (bf16*)(ws + off); off += (size_t)4096 * 256 * 2;     // 2.1 MB
    bf16* t3 = (bf16*)(ws + off); off += (size_t)1024 * 256 * 2;     // 0.5 MB
    (void)off;

    // 1) weight casts/transposes + b4 + zeros
    prep_w<<<1345, 256, 0, stream>>>(W1, W2, b2, w1t, w2t, w2b, b4, zbuf);

    // 2) W4T products (2-barrier; tiny)
    gemm128<3, false><<<dim3(2, 2, 4), 256, 0, stream>>>(
        w2t, w2b, nullptr, w4t, 256, 256, 512, 256, 1024, nullptr);

    // 3) projected embedding table: proj = emb @ W1 + b1  (2-barrier)
    gemm128<2, false><<<dim3(MP / 128, 2), 256, 0, stream>>>(
        emb, w1t, b1, proj, MP, KP1, WD, KP1, 256, zbuf);

    // 4) main: leaves + levels 0-1 fused, full-N blocks (gather once per row)
    gemm512<1, false, false><<<512, 512, 0, stream>>>(
        proj, ids, w4t, b4, h, 1024);

    // 5) tail: W4 steps, full-N + 3-stage pipeline (small grids)
    gemm512<0, true, false><<<128, 512, 0, stream>>>(h,  nullptr, w4t, b4, t1, 1024);
    gemm512<0, true, false><<<32,  512, 0, stream>>>(t1, nullptr, w4t, b4, t2, 1024);
    gemm512<0, true, false><<<8,   512, 0, stream>>>(t2, nullptr, w4t, b4, t3, 1024);
    gemm512<0, true, true><<<2,    512, 0, stream>>>(t3, nullptr, w4t, b4, d_out, 1024);
}

// Round 6
// 265.648 us; speedup vs baseline: 1.4758x; 1.0019x over previous
//
#include <hip/hip_runtime.h>
#include <hip/hip_bf16.h>
#include <stdint.h>

#define VOCAB 50257
#define WD 300
#define KP1 320              // word dim padded to mult of 32
#define MP 50432             // vocab rows padded: 394*128

using bf16 = __hip_bfloat16;
typedef __attribute__((ext_vector_type(4))) float f32x4;
typedef __attribute__((ext_vector_type(8))) short bf16x8;

// async global->LDS, 16B per lane; LDS dest = wave-uniform base + lane*16
__device__ __forceinline__ void async_load16(const void* g, void* l) {
    __builtin_amdgcn_global_load_lds(
        (const __attribute__((address_space(1))) uint32_t*)(uintptr_t)g,
        (__attribute__((address_space(3))) uint32_t*)l, 16, 0, 0);
}

// ---------- prep: w1t = W1^T bf16 [256x320]; w2t = W2^T bf16 [256x512];
//                  w2b = W2 cast bf16 [512x256]; b4 = b2@(A+B)+b2; zbuf zeros
__global__ void prep_w(const float* __restrict__ W1, const float* __restrict__ W2,
                       const float* __restrict__ b2,
                       bf16* __restrict__ w1t, bf16* __restrict__ w2t,
                       bf16* __restrict__ w2b, float* __restrict__ b4,
                       float* __restrict__ zbuf) {
    if (blockIdx.x == 1344) {           // bias block: b4 = b2@(A+B) + b2
        __shared__ float b2s[256];
        int n = threadIdx.x;
        b2s[n] = b2[n];
        __syncthreads();
        float acc = b2s[n];
        #pragma unroll 8
        for (int k = 0; k < 256; ++k)
            acc += b2s[k] * (W2[k * 256 + n] + W2[(k + 256) * 256 + n]);
        b4[n] = acc;
        if (n < 16) zbuf[n] = 0.0f;
        return;
    }
    int idx = blockIdx.x * 256 + threadIdx.x;
    if (idx < 256 * KP1) {                              // w1t
        int n = idx / KP1;
        int k = idx - n * KP1;
        w1t[idx] = __float2bfloat16(k < WD ? W1[k * 256 + n] : 0.0f);
    } else if (idx < 256 * KP1 + 131072) {              // w2t
        int j = idx - 256 * KP1;
        int n = j >> 9, k = j & 511;
        w2t[j] = __float2bfloat16(W2[k * 256 + n]);
    } else {                                            // w2b: plain cast
        int j = idx - 256 * KP1 - 131072;
        w2b[j] = __float2bfloat16(W2[j]);
    }
}

// ---------- gemm128: 128x128 tile, 4 waves, m97 2-barrier (W4T only) ---------
// AMODE 3: W4 products: grid.z = j; A-op = w2t + 256*(j>>1), BT = w2b + 65536*(j&1)
template <int AMODE, bool OUT_F32>
__global__ __launch_bounds__(256)
void gemm128(const void* __restrict__ Av, const bf16* __restrict__ BT,
             const float* __restrict__ bias, void* __restrict__ C,
             int M, int K, int As, int Bstr, int Cs) {
    __shared__ char smem[8192 + 8192];
    char* Asm = smem;
    bf16* Bsm = (bf16*)(smem + 8192);

    const int t = threadIdx.x, w = t >> 6, lane = t & 63;
    const int wr = w >> 1, wc = w & 1, mi = lane & 15, q = lane >> 4;
    const int m0 = blockIdx.x * 128, n0 = blockIdx.y * 128;

    const bf16* Ab = (const bf16*)Av;
    const bf16* BTp = BT;
    int coff = 0;
    if constexpr (AMODE == 3) {
        int j = blockIdx.z;
        Ab = (const bf16*)Av + 256 * (j >> 1);
        BTp = BT + 65536 * (j & 1);
        coff = 256 * j;
    }

    f32x4 acc[4][4] = {};

    for (int k0 = 0; k0 < K; k0 += 32) {
        #pragma unroll
        for (int i = 0; i < 2; ++i) {
            int s = i * 256 + t;
            int row = s >> 2;
            int kcd = (s & 3) ^ ((row >> 2) & 3);
            async_load16(Ab + (size_t)(m0 + row) * As + k0 + kcd * 8,
                         Asm + i * 4096 + w * 1024);
        }
        #pragma unroll
        for (int i = 0; i < 2; ++i) {
            int s = i * 256 + t;
            int col = s >> 2;
            int kcd = (s & 3) ^ ((col >> 2) & 3);
            async_load16(BTp + (size_t)(n0 + col) * Bstr + k0 + kcd * 8,
                         (char*)Bsm + i * 4096 + w * 1024);
        }
        __syncthreads();

        bf16x8 af[4], bfr[4];
        const bf16* As16 = (const bf16*)Asm;
        #pragma unroll
        for (int r = 0; r < 4; ++r) {
            int row = wr * 64 + r * 16 + mi;
            int slot = row * 4 + (q ^ ((row >> 2) & 3));
            af[r] = *(const bf16x8*)(As16 + slot * 8);
        }
        #pragma unroll
        for (int c = 0; c < 4; ++c) {
            int col = wc * 64 + c * 16 + mi;
            int slot = col * 4 + (q ^ ((col >> 2) & 3));
            bfr[c] = *(const bf16x8*)(Bsm + slot * 8);
        }
        #pragma unroll
        for (int r = 0; r < 4; ++r)
            #pragma unroll
            for (int c = 0; c < 4; ++c)
                acc[r][c] = __builtin_amdgcn_mfma_f32_16x16x32_bf16(af[r], bfr[c], acc[r][c], 0, 0, 0);
        __syncthreads();
    }

    #pragma unroll
    for (int r = 0; r < 4; ++r) {
        int rowb = m0 + wr * 64 + r * 16 + q * 4;
        #pragma unroll
        for (int c = 0; c < 4; ++c) {
            int col = n0 + wc * 64 + c * 16 + mi;
            float bv = (AMODE == 3) ? 0.0f : bias[col];
            #pragma unroll
            for (int i = 0; i < 4; ++i) {
                float v = acc[r][c][i] + bv;
                size_t o = (size_t)(rowb + i) * Cs + coff + col;
                if (OUT_F32) ((float*)C)[o] = v;
                else         ((bf16*)C)[o] = __float2bfloat16(v);
            }
        }
    }
}

// ---------- gemm512: 128-row x FULL-256-col tile, 8 waves (2 rg x 4 cg) ------
// AMODE 0: A bf16 [M x K] contiguous (tail W4 steps)
// AMODE 1: A row r = concat4(proj[ids4[m0+r]]), K = 1024 (fused leaf gather)
// AMODE 2: A fp32 emb rows (stride WD, rows clamped to VOCAB-1), K = KP1
// PIPE: 3-stage LDS pipeline w/ fine vmcnt (small grids only); else 2-barrier.
template <int AMODE, bool PIPE, bool OUT_F32>
__global__ __launch_bounds__(512)
void gemm512(const void* __restrict__ Av, const int* __restrict__ ids,
             const bf16* __restrict__ BT, const float* __restrict__ bias,
             void* __restrict__ C, int K, const float* __restrict__ zbuf) {
    constexpr int ASZ = (AMODE == 2) ? 16384 : 8192;
    constexpr int BSZ = 16384, STAGE = ASZ + BSZ;
    __shared__ char smem[PIPE ? 3 * STAGE : STAGE];

    const int t = threadIdx.x, w = t >> 6, lane = t & 63;
    const int rg = w >> 2, cg = w & 3, mi = lane & 15, q = lane >> 4;
    const int m0 = blockIdx.x * 128;
    const bf16* Ab = (const bf16*)Av;

    int4 idq = {0, 0, 0, 0};
    if constexpr (AMODE == 1) idq = ((const int4*)ids)[m0 + (t >> 2)];

    auto stage = [&](int ke, int buf) {
        char* Asm = smem + buf * STAGE;
        char* Bsm = Asm + ASZ;
        if constexpr (AMODE == 2) {
            const float* A32 = (const float*)Av;
            #pragma unroll
            for (int i = 0; i < 2; ++i) {               // 1024 fp32x4 chunks
                int s = i * 512 + t;
                int row = s >> 3;
                int kcd = (s & 7) ^ (row & 7);
                int k = ke + kcd * 4;
                int grow = m0 + row; if (grow >= VOCAB) grow = VOCAB - 1;
                const float* g = (k <= 296) ? (A32 + (size_t)grow * WD + k) : zbuf;
                async_load16(g, Asm + i * 8192 + w * 1024);
            }
        } else {
            int row = t >> 2;                           // 512 bf16x8 chunks, 1/thread
            int kcd = (t & 3) ^ ((row >> 2) & 3);
            const bf16* g;
            if constexpr (AMODE == 1) {
                int sel = ke >> 8;                      // leaf slot, wave-uniform
                int id = (sel & 2) ? ((sel & 1) ? idq.w : idq.z)
                                   : ((sel & 1) ? idq.y : idq.x);
                g = Ab + (size_t)id * 256 + (ke & 255) + kcd * 8;
            } else {
                g = Ab + (size_t)(m0 + row) * K + ke + kcd * 8;
            }
            async_load16(g, Asm + w * 1024);
        }
        #pragma unroll
        for (int i = 0; i < 2; ++i) {                   // B: 1024 chunks, 2/thread
            int s = i * 512 + t;
            int col = s >> 2;
            int kcd = (s & 3) ^ ((col >> 2) & 3);
            async_load16(BT + (size_t)col * K + ke + kcd * 8,
                         Bsm + i * 8192 + w * 1024);
        }
    };

    f32x4 acc[4][4] = {};

    auto compute = [&](int buf) {
        const char* Asm = smem + buf * STAGE;
        const bf16* Bs16 = (const bf16*)(Asm + ASZ);
        bf16x8 af[4], bfr[4];
        if constexpr (AMODE == 2) {
            const float* As32 = (const float*)Asm;
            #pragma unroll
            for (int r = 0; r < 4; ++r) {
                int row = rg * 64 + r * 16 + mi;
                int sl = row * 8 + ((2 * q) ^ (row & 7));
                f32x4 lo = *(const f32x4*)(As32 + sl * 4);
                f32x4 hi = *(const f32x4*)(As32 + (sl ^ 1) * 4);
                union { bf16x8 v; bf16 h[8]; } u;
                #pragma unroll
                for (int j = 0; j < 4; ++j) u.h[j] = __float2bfloat16(lo[j]);
                #pragma unroll
                for (int j = 0; j < 4; ++j) u.h[4 + j] = __float2bfloat16(hi[j]);
                af[r] = u.v;
            }
        } else {
            const bf16* As16 = (const bf16*)Asm;
            #pragma unroll
            for (int r = 0; r < 4; ++r) {
                int row = rg * 64 + r * 16 + mi;
                int slot = row * 4 + (q ^ ((row >> 2) & 3));
                af[r] = *(const bf16x8*)(As16 + slot * 8);
            }
        }
        #pragma unroll
        for (int c = 0; c < 4; ++c) {
            int col = cg * 64 + c * 16 + mi;
            int slot = col * 4 + (q ^ ((col >> 2) & 3));
            bfr[c] = *(const bf16x8*)(Bs16 + slot * 8);
        }
        #pragma unroll
        for (int r = 0; r < 4; ++r)
            #pragma unroll
            for (int c = 0; c < 4; ++c)
                acc[r][c] = __builtin_amdgcn_mfma_f32_16x16x32_bf16(af[r], bfr[c], acc[r][c], 0, 0, 0);
    };

    const int S = K >> 5;
    if constexpr (!PIPE) {
        for (int k0 = 0; k0 < S; ++k0) {
            stage(k0 * 32, 0);
            __syncthreads();
            compute(0);
            __syncthreads();
        }
    } else {
        stage(0, 0);
        if (S > 1) stage(32, 1);
        for (int k0 = 0; k0 < S; ++k0) {
            if (k0 + 1 < S)
                asm volatile("s_waitcnt vmcnt(3)\n\ts_barrier" ::: "memory");
            else
                asm volatile("s_waitcnt vmcnt(0)\n\ts_barrier" ::: "memory");
            if (k0 + 2 < S) stage((k0 + 2) * 32, (k0 + 2) % 3);
            compute(k0 % 3);
        }
    }

    // epilogue: C/D layout col = lane&15, row = (lane>>4)*4 + i
    #pragma unroll
    for (int r = 0; r < 4; ++r) {
        int rowb = m0 + rg * 64 + r * 16 + q * 4;
        #pragma unroll
        for (int c = 0; c < 4; ++c) {
            int col = cg * 64 + c * 16 + mi;
            float bv = bias[col];
            #pragma unroll
            for (int i = 0; i < 4; ++i) {
                float v = acc[r][c][i] + bv;
                size_t o = (size_t)(rowb + i) * 256 + col;
                if (OUT_F32) ((float*)C)[o] = v;
                else         ((bf16*)C)[o] = __float2bfloat16(v);
            }
        }
    }
}

extern "C" void kernel_launch(void* const* d_in, const int* in_sizes, int n_in,
                              void* d_out, int out_size, void* d_ws, size_t ws_size,
                              hipStream_t stream) {
    const int*   ids = (const int*)d_in[0];
    const float* emb = (const float*)d_in[1];
    const float* W1  = (const float*)d_in[2];
    const float* b1  = (const float*)d_in[3];
    const float* W2  = (const float*)d_in[4];
    const float* b2  = (const float*)d_in[5];
    (void)in_sizes; (void)n_in; (void)out_size; (void)ws_size;

    char* ws = (char*)d_ws;
    size_t off = 0;
    float* zbuf = (float*)(ws + off); off += 1024;
    float* b4   = (float*)(ws + off); off += 1024;
    bf16* w1t = (bf16*)(ws + off); off += (size_t)256 * KP1 * 2;     // 160 KB
    bf16* w2t = (bf16*)(ws + off); off += (size_t)256 * 512 * 2;     // 256 KB
    bf16* w2b = (bf16*)(ws + off); off += (size_t)512 * 256 * 2;     // 256 KB
    bf16* w4t = (bf16*)(ws + off); off += (size_t)256 * 1024 * 2;    // 512 KB
    bf16* proj = (bf16*)(ws + off); off += (size_t)MP * 256 * 2;     // 25.8 MB
    bf16* h  = (bf16*)(ws + off); off += (size_t)65536 * 256 * 2;    // 33.5 MB
    bf16* t1 = (bf16*)(ws + off); off += (size_t)16384 * 256 * 2;    // 8.4 MB
    bf16* t2 = (bf16*)(ws + off); off += (size_t)4096 * 256 * 2;     // 2.1 MB
    bf16* t3 = (bf16*)(ws + off); off += (size_t)1024 * 256 * 2;     // 0.5 MB
    (void)off;

    // 1) weight casts/transposes + b4 + zeros
    prep_w<<<1345, 256, 0, stream>>>(W1, W2, b2, w1t, w2t, w2b, b4, zbuf);

    // 2) W4T products (2-barrier; tiny)
    gemm128<3, false><<<dim3(2, 2, 4), 256, 0, stream>>>(
        w2t, w2b, nullptr, w4t, 256, 256, 512, 256, 1024);

    // 3) projected embedding table: proj = emb @ W1 + b1  (full-N: emb read once)
    gemm512<2, false, false><<<MP / 128, 512, 0, stream>>>(
        emb, nullptr, w1t, b1, proj, KP1, zbuf);

    // 4) main: leaves + levels 0-1 fused, full-N blocks (gather once per row)
    gemm512<1, false, false><<<512, 512, 0, stream>>>(
        proj, ids, w4t, b4, h, 1024, nullptr);

    // 5) tail: W4 steps, full-N + 3-stage pipeline (small grids)
    gemm512<0, true, false><<<128, 512, 0, stream>>>(h,  nullptr, w4t, b4, t1, 1024, nullptr);
    gemm512<0, true, false><<<32,  512, 0, stream>>>(t1, nullptr, w4t, b4, t2, 1024, nullptr);
    gemm512<0, true, false><<<8,   512, 0, stream>>>(t2, nullptr, w4t, b4, t3, 1024, nullptr);
    gemm512<0, true, true><<<2,    512, 0, stream>>>(t3, nullptr, w4t, b4, d_out, 1024, nullptr);
}

// Round 7
// 249.324 us; speedup vs baseline: 1.5724x; 1.0655x over previous
//
#include <hip/hip_runtime.h>
#include <hip/hip_bf16.h>
#include <stdint.h>

#define VOCAB 50257
#define WD 300
#define KP1 320              // word dim padded to mult of 32
#define MP 50432             // vocab rows padded: 394*128

using bf16 = __hip_bfloat16;
typedef __attribute__((ext_vector_type(4))) float f32x4;
typedef __attribute__((ext_vector_type(8))) short bf16x8;

// async global->LDS, 16B per lane; LDS dest = wave-uniform base + lane*16
__device__ __forceinline__ void async_load16(const void* g, void* l) {
    __builtin_amdgcn_global_load_lds(
        (const __attribute__((address_space(1))) uint32_t*)(uintptr_t)g,
        (__attribute__((address_space(3))) uint32_t*)l, 16, 0, 0);
}

// ---------- prep: w1t = W1^T bf16 [256x320]; w2t = W2^T bf16 [256x512];
//                  w2b = W2 cast bf16 [512x256]; b4 = b2@(A+B)+b2; zbuf zeros
__global__ void prep_w(const float* __restrict__ W1, const float* __restrict__ W2,
                       const float* __restrict__ b2,
                       bf16* __restrict__ w1t, bf16* __restrict__ w2t,
                       bf16* __restrict__ w2b, float* __restrict__ b4,
                       float* __restrict__ zbuf) {
    if (blockIdx.x == 1344) {           // bias block: b4 = b2@(A+B) + b2
        __shared__ float b2s[256];
        int n = threadIdx.x;
        b2s[n] = b2[n];
        __syncthreads();
        float acc = b2s[n];
        #pragma unroll 8
        for (int k = 0; k < 256; ++k)
            acc += b2s[k] * (W2[k * 256 + n] + W2[(k + 256) * 256 + n]);
        b4[n] = acc;
        if (n < 16) zbuf[n] = 0.0f;
        return;
    }
    int idx = blockIdx.x * 256 + threadIdx.x;
    if (idx < 256 * KP1) {                              // w1t
        int n = idx / KP1;
        int k = idx - n * KP1;
        w1t[idx] = __float2bfloat16(k < WD ? W1[k * 256 + n] : 0.0f);
    } else if (idx < 256 * KP1 + 131072) {              // w2t
        int j = idx - 256 * KP1;
        int n = j >> 9, k = j & 511;
        w2t[j] = __float2bfloat16(W2[k * 256 + n]);
    } else {                                            // w2b: plain cast
        int j = idx - 256 * KP1 - 131072;
        w2b[j] = __float2bfloat16(W2[j]);
    }
}

// ---------- gemm128: 128x128 tile, 4 waves, m97 2-barrier (W4T only) ---------
// AMODE 3: W4 products: grid.z = j; A-op = w2t + 256*(j>>1), BT = w2b + 65536*(j&1)
template <int AMODE, bool OUT_F32>
__global__ __launch_bounds__(256)
void gemm128(const void* __restrict__ Av, const bf16* __restrict__ BT,
             const float* __restrict__ bias, void* __restrict__ C,
             int M, int K, int As, int Bstr, int Cs) {
    __shared__ char smem[8192 + 8192];
    char* Asm = smem;
    bf16* Bsm = (bf16*)(smem + 8192);

    const int t = threadIdx.x, w = t >> 6, lane = t & 63;
    const int wr = w >> 1, wc = w & 1, mi = lane & 15, q = lane >> 4;
    const int m0 = blockIdx.x * 128, n0 = blockIdx.y * 128;

    const bf16* Ab = (const bf16*)Av;
    const bf16* BTp = BT;
    int coff = 0;
    if constexpr (AMODE == 3) {
        int j = blockIdx.z;
        Ab = (const bf16*)Av + 256 * (j >> 1);
        BTp = BT + 65536 * (j & 1);
        coff = 256 * j;
    }

    f32x4 acc[4][4] = {};

    for (int k0 = 0; k0 < K; k0 += 32) {
        #pragma unroll
        for (int i = 0; i < 2; ++i) {
            int s = i * 256 + t;
            int row = s >> 2;
            int kcd = (s & 3) ^ ((row >> 2) & 3);
            async_load16(Ab + (size_t)(m0 + row) * As + k0 + kcd * 8,
                         Asm + i * 4096 + w * 1024);
        }
        #pragma unroll
        for (int i = 0; i < 2; ++i) {
            int s = i * 256 + t;
            int col = s >> 2;
            int kcd = (s & 3) ^ ((col >> 2) & 3);
            async_load16(BTp + (size_t)(n0 + col) * Bstr + k0 + kcd * 8,
                         (char*)Bsm + i * 4096 + w * 1024);
        }
        __syncthreads();

        bf16x8 af[4], bfr[4];
        const bf16* As16 = (const bf16*)Asm;
        #pragma unroll
        for (int r = 0; r < 4; ++r) {
            int row = wr * 64 + r * 16 + mi;
            int slot = row * 4 + (q ^ ((row >> 2) & 3));
            af[r] = *(const bf16x8*)(As16 + slot * 8);
        }
        #pragma unroll
        for (int c = 0; c < 4; ++c) {
            int col = wc * 64 + c * 16 + mi;
            int slot = col * 4 + (q ^ ((col >> 2) & 3));
            bfr[c] = *(const bf16x8*)(Bsm + slot * 8);
        }
        #pragma unroll
        for (int r = 0; r < 4; ++r)
            #pragma unroll
            for (int c = 0; c < 4; ++c)
                acc[r][c] = __builtin_amdgcn_mfma_f32_16x16x32_bf16(af[r], bfr[c], acc[r][c], 0, 0, 0);
        __syncthreads();
    }

    #pragma unroll
    for (int r = 0; r < 4; ++r) {
        int rowb = m0 + wr * 64 + r * 16 + q * 4;
        #pragma unroll
        for (int c = 0; c < 4; ++c) {
            int col = n0 + wc * 64 + c * 16 + mi;
            float bv = (AMODE == 3) ? 0.0f : bias[col];
            #pragma unroll
            for (int i = 0; i < 4; ++i) {
                float v = acc[r][c][i] + bv;
                size_t o = (size_t)(rowb + i) * Cs + coff + col;
                if (OUT_F32) ((float*)C)[o] = v;
                else         ((bf16*)C)[o] = __float2bfloat16(v);
            }
        }
    }
}

// ---------- gemm512: 128-row x FULL-256-col tile, 8 waves (2 rg x 4 cg) ------
// AMODE 0: A bf16 [M x K] contiguous
// AMODE 1: A row r = concat4(proj[ids4[m0+r]]), K = 1024 (fused leaf gather)
// AMODE 2: A fp32 emb rows (stride WD, rows clamped to VOCAB-1), K = KP1
// PIPE: 3-stage LDS pipeline, fine vmcnt — use when blocks/CU <= 2 anyway.
template <int AMODE, bool PIPE, bool OUT_F32>
__global__ __launch_bounds__(512)
void gemm512(const void* __restrict__ Av, const int* __restrict__ ids,
             const bf16* __restrict__ BT, const float* __restrict__ bias,
             void* __restrict__ C, int K, const float* __restrict__ zbuf) {
    constexpr int ASZ = (AMODE == 2) ? 16384 : 8192;
    constexpr int BSZ = 16384, STAGE = ASZ + BSZ;
    __shared__ char smem[PIPE ? 3 * STAGE : STAGE];

    const int t = threadIdx.x, w = t >> 6, lane = t & 63;
    const int rg = w >> 2, cg = w & 3, mi = lane & 15, q = lane >> 4;
    const int m0 = blockIdx.x * 128;
    const bf16* Ab = (const bf16*)Av;

    int4 idq = {0, 0, 0, 0};
    if constexpr (AMODE == 1) idq = ((const int4*)ids)[m0 + (t >> 2)];

    auto stage = [&](int ke, int buf) {
        char* Asm = smem + buf * STAGE;
        char* Bsm = Asm + ASZ;
        if constexpr (AMODE == 2) {
            const float* A32 = (const float*)Av;
            #pragma unroll
            for (int i = 0; i < 2; ++i) {               // 1024 fp32x4 chunks
                int s = i * 512 + t;
                int row = s >> 3;
                int kcd = (s & 7) ^ (row & 7);
                int k = ke + kcd * 4;
                int grow = m0 + row; if (grow >= VOCAB) grow = VOCAB - 1;
                const float* g = (k <= 296) ? (A32 + (size_t)grow * WD + k) : zbuf;
                async_load16(g, Asm + i * 8192 + w * 1024);
            }
        } else {
            int row = t >> 2;                           // 512 bf16x8 chunks, 1/thread
            int kcd = (t & 3) ^ ((row >> 2) & 3);
            const bf16* g;
            if constexpr (AMODE == 1) {
                int sel = ke >> 8;                      // leaf slot, wave-uniform
                int id = (sel & 2) ? ((sel & 1) ? idq.w : idq.z)
                                   : ((sel & 1) ? idq.y : idq.x);
                g = Ab + (size_t)id * 256 + (ke & 255) + kcd * 8;
            } else {
                g = Ab + (size_t)(m0 + row) * K + ke + kcd * 8;
            }
            async_load16(g, Asm + w * 1024);
        }
        #pragma unroll
        for (int i = 0; i < 2; ++i) {                   // B: 1024 chunks, 2/thread
            int s = i * 512 + t;
            int col = s >> 2;
            int kcd = (s & 3) ^ ((col >> 2) & 3);
            async_load16(BT + (size_t)col * K + ke + kcd * 8,
                         Bsm + i * 8192 + w * 1024);
        }
    };

    f32x4 acc[4][4] = {};

    auto compute = [&](int buf) {
        const char* Asm = smem + buf * STAGE;
        const bf16* Bs16 = (const bf16*)(Asm + ASZ);
        bf16x8 af[4], bfr[4];
        if constexpr (AMODE == 2) {
            const float* As32 = (const float*)Asm;
            #pragma unroll
            for (int r = 0; r < 4; ++r) {
                int row = rg * 64 + r * 16 + mi;
                int sl = row * 8 + ((2 * q) ^ (row & 7));
                f32x4 lo = *(const f32x4*)(As32 + sl * 4);
                f32x4 hi = *(const f32x4*)(As32 + (sl ^ 1) * 4);
                union { bf16x8 v; bf16 h[8]; } u;
                #pragma unroll
                for (int j = 0; j < 4; ++j) u.h[j] = __float2bfloat16(lo[j]);
                #pragma unroll
                for (int j = 0; j < 4; ++j) u.h[4 + j] = __float2bfloat16(hi[j]);
                af[r] = u.v;
            }
        } else {
            const bf16* As16 = (const bf16*)Asm;
            #pragma unroll
            for (int r = 0; r < 4; ++r) {
                int row = rg * 64 + r * 16 + mi;
                int slot = row * 4 + (q ^ ((row >> 2) & 3));
                af[r] = *(const bf16x8*)(As16 + slot * 8);
            }
        }
        #pragma unroll
        for (int c = 0; c < 4; ++c) {
            int col = cg * 64 + c * 16 + mi;
            int slot = col * 4 + (q ^ ((col >> 2) & 3));
            bfr[c] = *(const bf16x8*)(Bs16 + slot * 8);
        }
        #pragma unroll
        for (int r = 0; r < 4; ++r)
            #pragma unroll
            for (int c = 0; c < 4; ++c)
                acc[r][c] = __builtin_amdgcn_mfma_f32_16x16x32_bf16(af[r], bfr[c], acc[r][c], 0, 0, 0);
    };

    const int S = K >> 5;
    if constexpr (!PIPE) {
        for (int k0 = 0; k0 < S; ++k0) {
            stage(k0 * 32, 0);
            __syncthreads();
            compute(0);
            __syncthreads();
        }
    } else {
        stage(0, 0);
        if (S > 1) stage(32, 1);
        for (int k0 = 0; k0 < S; ++k0) {
            if (k0 + 1 < S) {
                if constexpr (AMODE == 2)
                    asm volatile("s_waitcnt vmcnt(4)\n\ts_barrier" ::: "memory");
                else
                    asm volatile("s_waitcnt vmcnt(3)\n\ts_barrier" ::: "memory");
            } else {
                asm volatile("s_waitcnt vmcnt(0)\n\ts_barrier" ::: "memory");
            }
            if (k0 + 2 < S) stage((k0 + 2) * 32, (k0 + 2) % 3);
            compute(k0 % 3);
        }
    }

    // epilogue: C/D layout col = lane&15, row = (lane>>4)*4 + i
    #pragma unroll
    for (int r = 0; r < 4; ++r) {
        int rowb = m0 + rg * 64 + r * 16 + q * 4;
        #pragma unroll
        for (int c = 0; c < 4; ++c) {
            int col = cg * 64 + c * 16 + mi;
            float bv = bias[col];
            #pragma unroll
            for (int i = 0; i < 4; ++i) {
                float v = acc[r][c][i] + bv;
                size_t o = (size_t)(rowb + i) * 256 + col;
                if (OUT_F32) ((float*)C)[o] = v;
                else         ((bf16*)C)[o] = __float2bfloat16(v);
            }
        }
    }
}

// ---------- tree3: last 3 W4 levels per tree in one dispatch -----------------
// Input: t1 = 16384 rows x 256 (64 rows/tree, contiguous). Per block (1 tree):
// 64 rows -> 16 -> 4 -> 1 (root, fp32 to out). B-frags read directly from w4t
// (L2-resident); no barriers inside a level's K-loop. 8 waves x 32 cols each.
__global__ __launch_bounds__(512)
void tree3(const bf16* __restrict__ Hin, const bf16* __restrict__ w4t,
           const float* __restrict__ b4, float* __restrict__ out) {
    __shared__ bf16 Ha[64 * 256];   // 32 KB, swizzled chunks
    __shared__ bf16 Hb[16 * 256];   // 8 KB
    __shared__ bf16 Hc[4 * 256];    // 2 KB, plain (broadcast reads)

    const int t = threadIdx.x, w = t >> 6, lane = t & 63;
    const int mi = lane & 15, q = lane >> 4;
    const int tree = blockIdx.x;
    const bf16* src = Hin + (size_t)tree * 64 * 256;
    const int cb0 = w * 32;                       // this wave's col base

    // stage 64 rows: chunk slot (row, cs) holds source chunk cs ^ ((row>>2)&7)
    #pragma unroll
    for (int i = 0; i < 4; ++i) {
        int s = i * 512 + t;
        int row = s >> 5;
        int cs = s & 31;
        async_load16(src + row * 256 + (cs ^ ((row >> 2) & 7)) * 8,
                     (char*)Ha + i * 8192 + w * 1024);
    }
    __syncthreads();

    float bv[2];
    #pragma unroll
    for (int c = 0; c < 2; ++c) bv[c] = b4[cb0 + c * 16 + mi];

    // ---- level 1: 64 rows (view 16 x 1024) -> Hb 16 x 256 ----
    {
        f32x4 acc[2] = {};
        #pragma unroll 4
        for (int k0 = 0; k0 < 1024; k0 += 32) {
            int sel = k0 >> 8;
            int kc = ((k0 & 255) >> 3) + q;
            int row4 = 4 * mi + sel;
            bf16x8 a = *(const bf16x8*)(Ha + (row4 * 32 + (kc ^ (mi & 7))) * 8);
            #pragma unroll
            for (int c = 0; c < 2; ++c) {
                bf16x8 b = *(const bf16x8*)(w4t + (size_t)(cb0 + c * 16 + mi) * 1024 + k0 + q * 8);
                acc[c] = __builtin_amdgcn_mfma_f32_16x16x32_bf16(a, b, acc[c], 0, 0, 0);
            }
        }
        #pragma unroll
        for (int c = 0; c < 2; ++c) {
            int col = cb0 + c * 16 + mi;
            int kc2 = col >> 3;
            #pragma unroll
            for (int i = 0; i < 4; ++i) {
                int row = q * 4 + i;
                int slot = row * 32 + (kc2 ^ ((row >> 2) & 7));
                Hb[slot * 8 + (col & 7)] = __float2bfloat16(acc[c][i] + bv[c]);
            }
        }
    }
    __syncthreads();

    // ---- level 2: 16 rows (view 4 x 1024) -> Hc 4 x 256 ----
    {
        f32x4 acc[2] = {};
        #pragma unroll 4
        for (int k0 = 0; k0 < 1024; k0 += 32) {
            int sel = k0 >> 8;
            int kc = ((k0 & 255) >> 3) + q;
            int row4 = 4 * mi + sel; if (row4 > 15) row4 = 15;   // clamp (rows>3 unused)
            bf16x8 a = *(const bf16x8*)(Hb + (row4 * 32 + (kc ^ ((row4 >> 2) & 7))) * 8);
            #pragma unroll
            for (int c = 0; c < 2; ++c) {
                bf16x8 b = *(const bf16x8*)(w4t + (size_t)(cb0 + c * 16 + mi) * 1024 + k0 + q * 8);
                acc[c] = __builtin_amdgcn_mfma_f32_16x16x32_bf16(a, b, acc[c], 0, 0, 0);
            }
        }
        if (q == 0) {                                  // rows 0..3 live in q=0, i=0..3
            #pragma unroll
            for (int c = 0; c < 2; ++c) {
                int col = cb0 + c * 16 + mi;
                #pragma unroll
                for (int i = 0; i < 4; ++i)
                    Hc[i * 256 + col] = __float2bfloat16(acc[c][i] + bv[c]);
            }
        }
    }
    __syncthreads();

    // ---- level 3: 4 rows (view 1 x 1024) -> root fp32 ----
    {
        f32x4 acc[2] = {};
        #pragma unroll 4
        for (int k0 = 0; k0 < 1024; k0 += 32) {
            int srow = k0 >> 8;
            int kc = ((k0 & 255) >> 3) + q;
            bf16x8 a = *(const bf16x8*)(Hc + srow * 256 + kc * 8);   // broadcast
            #pragma unroll
            for (int c = 0; c < 2; ++c) {
                bf16x8 b = *(const bf16x8*)(w4t + (size_t)(cb0 + c * 16 + mi) * 1024 + k0 + q * 8);
                acc[c] = __builtin_amdgcn_mfma_f32_16x16x32_bf16(a, b, acc[c], 0, 0, 0);
            }
        }
        if (q == 0) {                                  // root row = q=0, i=0
            #pragma unroll
            for (int c = 0; c < 2; ++c) {
                int col = cb0 + c * 16 + mi;
                out[(size_t)tree * 256 + col] = acc[c][0] + bv[c];
            }
        }
    }
}

extern "C" void kernel_launch(void* const* d_in, const int* in_sizes, int n_in,
                              void* d_out, int out_size, void* d_ws, size_t ws_size,
                              hipStream_t stream) {
    const int*   ids = (const int*)d_in[0];
    const float* emb = (const float*)d_in[1];
    const float* W1  = (const float*)d_in[2];
    const float* b1  = (const float*)d_in[3];
    const float* W2  = (const float*)d_in[4];
    const float* b2  = (const float*)d_in[5];
    (void)in_sizes; (void)n_in; (void)out_size; (void)ws_size;

    char* ws = (char*)d_ws;
    size_t off = 0;
    float* zbuf = (float*)(ws + off); off += 1024;
    float* b4   = (float*)(ws + off); off += 1024;
    bf16* w1t = (bf16*)(ws + off); off += (size_t)256 * KP1 * 2;     // 160 KB
    bf16* w2t = (bf16*)(ws + off); off += (size_t)256 * 512 * 2;     // 256 KB
    bf16* w2b = (bf16*)(ws + off); off += (size_t)512 * 256 * 2;     // 256 KB
    bf16* w4t = (bf16*)(ws + off); off += (size_t)256 * 1024 * 2;    // 512 KB
    bf16* proj = (bf16*)(ws + off); off += (size_t)MP * 256 * 2;     // 25.8 MB
    bf16* h  = (bf16*)(ws + off); off += (size_t)65536 * 256 * 2;    // 33.5 MB
    bf16* t1 = (bf16*)(ws + off); off += (size_t)16384 * 256 * 2;    // 8.4 MB
    (void)off;

    // 1) weight casts/transposes + b4 + zeros
    prep_w<<<1345, 256, 0, stream>>>(W1, W2, b2, w1t, w2t, w2b, b4, zbuf);

    // 2) W4T products (2-barrier; tiny)
    gemm128<3, false><<<dim3(2, 2, 4), 256, 0, stream>>>(
        w2t, w2b, nullptr, w4t, 256, 256, 512, 256, 1024);

    // 3) projected embedding table: proj = emb @ W1 + b1  (full-N: emb read once)
    gemm512<2, false, false><<<MP / 128, 512, 0, stream>>>(
        emb, nullptr, w1t, b1, proj, KP1, zbuf);

    // 4) main: leaves + levels 0-1 fused, full-N + 3-stage pipeline
    //    (grid 512 = 2 blocks/CU; 72 KB LDS keeps 2/CU -> pipeline is free)
    gemm512<1, true, false><<<512, 512, 0, stream>>>(
        proj, ids, w4t, b4, h, 1024, nullptr);

    // 5) t1: 65536 -> 16384 rows (full-N, pipelined)
    gemm512<0, true, false><<<128, 512, 0, stream>>>(h, nullptr, w4t, b4, t1, 1024, nullptr);

    // 6) last 3 levels per tree, single dispatch, roots fp32 to d_out
    tree3<<<256, 512, 0, stream>>>(t1, w4t, b4, (float*)d_out);
}